// Round 3
// baseline (309.163 us; speedup 1.0000x reference)
//
#include <hip/hip_runtime.h>
#include <hip/hip_fp16.h>
#include <cstdint>

typedef _Float16 f16x8 __attribute__((ext_vector_type(8)));
typedef _Float16 f16x4 __attribute__((ext_vector_type(4)));
typedef float    f32x4 __attribute__((ext_vector_type(4)));
typedef float    f32x16 __attribute__((ext_vector_type(16)));

#define MFMA16(a, b, c) __builtin_amdgcn_mfma_f32_16x16x32_f16((a), (b), (c), 0, 0, 0)
#define MFMA32(a, b, c) __builtin_amdgcn_mfma_f32_32x32x16_f16((a), (b), (c), 0, 0, 0)

// B=4, LQ=4096, LKV=256, D=1024, H=16, KVH=4, HD=64

__device__ __forceinline__ void async_cp16(const _Float16* g, _Float16* l) {
    __builtin_amdgcn_global_load_lds(
        (const __attribute__((address_space(1))) void*)g,
        (__attribute__((address_space(3))) void*)l, 16, 0, 0);
}

// ---------------------------------------------------------------------------
// fp32 -> fp16 convert for latents only (patches converted inside gemm8q).
// ---------------------------------------------------------------------------
__global__ __launch_bounds__(256) void cvt_lat(const float4* __restrict__ latents,
                                               f16x4* __restrict__ l16) {
    const int i = blockIdx.x * 256 + threadIdx.x;  // 262144 float4
    const float4 v = latents[i];
    f16x4 o;
    o[0] = (_Float16)v.x; o[1] = (_Float16)v.y;
    o[2] = (_Float16)v.z; o[3] = (_Float16)v.w;
    l16[i] = o;
}

// ---------------------------------------------------------------------------
// All 4 weight transposes (fp32 [K][N] -> fp16 [N][K]) in one launch.
// ---------------------------------------------------------------------------
__global__ __launch_bounds__(256) void transpose_all(
    const float* __restrict__ Wq, const float* __restrict__ Wk,
    const float* __restrict__ Wv, const float* __restrict__ Wo,
    _Float16* __restrict__ WqT, _Float16* __restrict__ WkvT,
    _Float16* __restrict__ WoT) {
    const int z = blockIdx.z;
    const float* W;
    _Float16* WT;
    int Nd;
    if (z == 0)      { W = Wq; WT = WqT;                       Nd = 1024; }
    else if (z == 1) { W = Wk; WT = WkvT;                      Nd = 256;  }
    else if (z == 2) { W = Wv; WT = WkvT + (size_t)256 * 1024; Nd = 256;  }
    else             { W = Wo; WT = WoT;                       Nd = 1024; }
    const int n0 = blockIdx.x * 64, k0 = blockIdx.y * 64;
    if (n0 >= Nd) return;

    __shared__ float T[64][65];
    const int tid = threadIdx.x;
    const int nl = tid & 63, kg = tid >> 6;
#pragma unroll
    for (int i = 0; i < 16; ++i) {
        const int kl = kg * 16 + i;
        T[kl][nl] = W[(size_t)(k0 + kl) * Nd + n0 + nl];
    }
    __syncthreads();
    const int kl = tid & 63;
#pragma unroll
    for (int i = 0; i < 16; ++i) {
        const int nl2 = kg * 16 + i;
        WT[(size_t)(n0 + nl2) * 1024 + k0 + kl] = (_Float16)T[kl][nl2];
    }
}

__global__ void catbias(const float* __restrict__ a, const float* __restrict__ b,
                        float* __restrict__ o) {
    const int i = threadIdx.x;  // 512 threads
    o[i] = (i < 256) ? a[i] : b[i - 256];
}

// ---------------------------------------------------------------------------
// Small-M GEMM (KV-proj only): old 2-barrier structure, 256x128 tile.
// ---------------------------------------------------------------------------
template <int EPI>
__global__ __launch_bounds__(256, 2) void gemm32(const _Float16* __restrict__ A,
                                                 const _Float16* __restrict__ BT,
                                                 const float* __restrict__ bias,
                                                 void* __restrict__ Cp,
                                                 const int* __restrict__ nfp) {
    constexpr int K = 1024;
    __shared__ _Float16 As[256 * 64];
    __shared__ _Float16 Bs[128 * 64];

    const int tid = threadIdx.x;
    const int lane = tid & 63, l31 = lane & 31, hh = lane >> 5;
    const int w = tid >> 6, wm = w >> 1, wn = w & 1;

    const int n0 = blockIdx.x * 128;
    const int m0 = blockIdx.y * 256;

    f32x16 acc[4][2];
#pragma unroll
    for (int mt = 0; mt < 4; ++mt)
#pragma unroll
        for (int nt = 0; nt < 2; ++nt)
#pragma unroll
            for (int v = 0; v < 16; ++v) acc[mt][nt][v] = 0.f;

    for (int k0 = 0; k0 < K; k0 += 64) {
#pragma unroll
        for (int i = 0; i < 8; ++i) {
            const int id = i * 256 + tid;
            const int r = id >> 3;
            const int c = (id & 7) ^ (r & 7);
            async_cp16(A + (size_t)(m0 + r) * K + k0 + c * 8,
                       As + i * 2048 + w * 512);
        }
#pragma unroll
        for (int i = 0; i < 4; ++i) {
            const int id = i * 256 + tid;
            const int r = id >> 3;
            const int c = (id & 7) ^ (r & 7);
            async_cp16(BT + (size_t)(n0 + r) * K + k0 + c * 8,
                       Bs + i * 2048 + w * 512);
        }
        __syncthreads();

#pragma unroll
        for (int kk = 0; kk < 4; ++kk) {
            f16x8 af[4], bf[2];
#pragma unroll
            for (int mt = 0; mt < 4; ++mt) {
                const int row = wm * 128 + mt * 32 + l31;
                const int pc = (kk * 2 + hh) ^ (row & 7);
                af[mt] = *(const f16x8*)&As[row * 64 + pc * 8];
            }
#pragma unroll
            for (int nt = 0; nt < 2; ++nt) {
                const int row = wn * 64 + nt * 32 + l31;
                const int pc = (kk * 2 + hh) ^ (row & 7);
                bf[nt] = *(const f16x8*)&Bs[row * 64 + pc * 8];
            }
#pragma unroll
            for (int mt = 0; mt < 4; ++mt)
#pragma unroll
                for (int nt = 0; nt < 2; ++nt)
                    acc[mt][nt] = MFMA32(af[mt], bf[nt], acc[mt][nt]);
        }
        __syncthreads();
    }

    const int nf = nfp[0];
    const int nbase = n0 + wn * 64;

    float bb[2];
#pragma unroll
    for (int nt = 0; nt < 2; ++nt) bb[nt] = bias[nbase + nt * 32 + l31];
#pragma unroll
    for (int mt = 0; mt < 4; ++mt)
#pragma unroll
        for (int nt = 0; nt < 2; ++nt)
#pragma unroll
            for (int v = 0; v < 16; ++v) acc[mt][nt][v] += bb[nt];

    {  // K/V fused (N=512)
        _Float16* kout = (_Float16*)Cp;
        _Float16* vout = kout + (size_t)4 * 4 * 256 * 64;
        if (nbase < 256) {
            const float l2b = 13.287712379549449f;
            const float inv = exp2f(-((float)l31 * (1.0f / 32.0f)) * l2b);
            const int dv = 256 / (nf > 1 ? nf : 1);
            const int kvh = nbase >> 6;
#pragma unroll
            for (int mt = 0; mt < 4; ++mt) {
#pragma unroll
                for (int v = 0; v < 16; ++v) {
                    const int m = m0 + wm * 128 + mt * 32 + (v & 3) + 8 * (v >> 2) + 4 * hh;
                    const int b = m >> 8, lkv = m & 255;
                    if (nf > 1) {
                        const int pos = lkv / dv;
                        float s, c;
                        __sincosf((float)pos * inv, &s, &c);
                        const float x1 = acc[mt][0][v], x2 = acc[mt][1][v];
                        acc[mt][0][v] = x1 * c - x2 * s;
                        acc[mt][1][v] = x2 * c + x1 * s;
                    }
#pragma unroll
                    for (int nt = 0; nt < 2; ++nt) {
                        const int hd = nt * 32 + l31;
                        kout[(((size_t)(b * 4 + kvh)) * 256 + lkv) * 64 + hd] =
                            (_Float16)acc[mt][nt][v];
                    }
                }
            }
        } else {
            const int kvh = (nbase - 256) >> 6;
#pragma unroll
            for (int mt = 0; mt < 4; ++mt) {
#pragma unroll
                for (int v = 0; v < 16; ++v) {
                    const int m = m0 + wm * 128 + mt * 32 + (v & 3) + 8 * (v >> 2) + 4 * hh;
                    const int b = m >> 8, lkv = m & 255;
                    // pi-permuted kv slot: swap the 16s bit below the 4s bits
                    const int s = (lkv & 0xE0) | ((lkv & 12) << 1) |
                                  ((lkv & 16) >> 2) | (lkv & 3);
#pragma unroll
                    for (int nt = 0; nt < 2; ++nt) {
                        const int hd = nt * 32 + l31;
                        vout[(((size_t)(b * 4 + kvh)) * 64 + hd) * 256 + s] =
                            (_Float16)acc[mt][nt][v];
                    }
                }
            }
        }
    }
}

// ---------------------------------------------------------------------------
// 8-phase 256x256 GEMM, fp16 A (O-proj).  Unchanged from round 2.
// ---------------------------------------------------------------------------
template <int EPI>
__global__ __launch_bounds__(512, 2) void gemm8p(const _Float16* __restrict__ A,
                                                 const _Float16* __restrict__ BT,
                                                 const float* __restrict__ bias,
                                                 void* __restrict__ Cp,
                                                 const int* __restrict__ nfp) {
    constexpr int K = 1024;
    __shared__ alignas(16) _Float16 lds[2][2][2][128 * 64];  // [buf][A=0/B=1][half]

    const int tid = threadIdx.x;
    const int lane = tid & 63, quad = lane >> 4, l15 = lane & 15;
    const int w = tid >> 6, wm = w >> 2, wn = w & 3;

    // bijective XCD swizzle: 256 blocks, 8 XCDs -> 32-block m-stripes
    int lin = blockIdx.x;
    lin = (lin & 7) * 32 + (lin >> 3);
    const int m0 = (lin >> 2) * 256;
    const int n0 = (lin & 3) * 256;

    f32x4 acc[8][4];
#pragma unroll
    for (int mf = 0; mf < 8; ++mf)
#pragma unroll
        for (int nf = 0; nf < 4; ++nf)
#pragma unroll
            for (int rr = 0; rr < 4; ++rr) acc[mf][nf][rr] = 0.f;

    f16x8 ra[4][2], rb[4][2];

#define STAGE(BUF, MAT, HALF, KK0)                                              \
    {                                                                           \
        const _Float16* g_ = (MAT) ? BT : A;                                    \
        const int rb_ = ((MAT) ? n0 : m0) + (HALF) * 128;                       \
        _Float16* dst_ = &lds[BUF][MAT][HALF][0];                               \
        _Pragma("unroll") for (int i_ = 0; i_ < 2; ++i_) {                      \
            const int id_ = i_ * 512 + tid;                                     \
            const int r_ = id_ >> 3;                                            \
            const int c_ = (id_ & 7) ^ (r_ & 7);                                \
            async_cp16(g_ + (size_t)(rb_ + r_) * K + (KK0) + c_ * 8,            \
                       dst_ + i_ * 4096 + w * 512);                             \
        }                                                                       \
    }

#define LDA4(BUF, MH)                                                           \
    _Pragma("unroll") for (int i_ = 0; i_ < 4; ++i_)                            \
    _Pragma("unroll") for (int ks_ = 0; ks_ < 2; ++ks_) {                       \
        const int row_ = ((MH) * 4 + i_) * 16 + l15;                            \
        ra[i_][ks_] = *(const f16x8*)&lds[BUF][0][wm]                           \
            [row_ * 64 + (((ks_ * 4 + quad) ^ (l15 & 7)) * 8)];                 \
    }

#define LDB2(BUF, NFROM)                                                        \
    _Pragma("unroll") for (int j_ = 0; j_ < 2; ++j_)                            \
    _Pragma("unroll") for (int ks_ = 0; ks_ < 2; ++ks_) {                       \
        const int nf_ = (NFROM) + j_;                                           \
        const int row_ = (wn & 1) * 64 + nf_ * 16 + l15;                        \
        rb[nf_][ks_] = *(const f16x8*)&lds[BUF][1][wn >> 1]                     \
            [row_ * 64 + (((ks_ * 4 + quad) ^ (l15 & 7)) * 8)];                 \
    }

#define QUAD(QM, QN)                                                            \
    {                                                                           \
        __builtin_amdgcn_s_setprio(1);                                          \
        _Pragma("unroll") for (int i_ = 0; i_ < 4; ++i_)                        \
        _Pragma("unroll") for (int j_ = 0; j_ < 2; ++j_)                        \
        _Pragma("unroll") for (int ks_ = 0; ks_ < 2; ++ks_)                     \
            acc[(QM) * 4 + i_][(QN) * 2 + j_] =                                 \
                MFMA16(ra[i_][ks_], rb[(QN) * 2 + j_][ks_],                     \
                       acc[(QM) * 4 + i_][(QN) * 2 + j_]);                      \
        __builtin_amdgcn_s_setprio(0);                                          \
    }

#define FENCE() asm volatile("" ::: "memory")
#define BARR()  FENCE(); __builtin_amdgcn_s_barrier(); FENCE()
#define LGKM0() asm volatile("s_waitcnt lgkmcnt(0)" ::: "memory");              \
                __builtin_amdgcn_sched_barrier(0)
#define VMC4()  asm volatile("s_waitcnt vmcnt(4)" ::: "memory")

    // prologue: tile0 (all 4 halves) + tile1 (B0, A0)
    STAGE(0, 1, 0, 0);
    STAGE(0, 1, 1, 0);
    STAGE(0, 0, 0, 0);
    STAGE(0, 0, 1, 0);
    STAGE(1, 1, 0, 64);
    STAGE(1, 0, 0, 64);
    VMC4();
    BARR();

    int k0 = 0;
#pragma unroll 1
    for (int it = 0; it < 8; ++it) {
        const int k_t1 = k0 + 64;
        const int k_n0 = (k0 + 128 < K) ? k0 + 128 : K - 64;  // tile t0+2
        const int k_n1 = (k0 + 192 < K) ? k0 + 192 : K - 64;  // tile t1+2
        // P0
        LDA4(0, 0); LDB2(0, 0);
        STAGE(1, 1, 1, k_t1);
        BARR(); LGKM0(); QUAD(0, 0); BARR();
        // P1
        LDB2(0, 2);
        STAGE(1, 0, 1, k_t1);
        BARR(); LGKM0(); QUAD(0, 1); BARR();
        // P2
        LDA4(0, 1);
        STAGE(0, 1, 0, k_n0);
        BARR(); LGKM0(); QUAD(1, 0); BARR();
        // P3
        STAGE(0, 1, 1, k_n0);
        BARR(); LGKM0(); QUAD(1, 1); VMC4(); BARR();
        // P4
        LDA4(1, 0); LDB2(1, 0);
        STAGE(0, 0, 0, k_n0);
        BARR(); LGKM0(); QUAD(0, 0); BARR();
        // P5
        LDB2(1, 2);
        STAGE(0, 0, 1, k_n0);
        BARR(); LGKM0(); QUAD(0, 1); BARR();
        // P6
        LDA4(1, 1);
        STAGE(1, 1, 0, k_n1);
        BARR(); LGKM0(); QUAD(1, 0); BARR();
        // P7
        STAGE(1, 0, 0, k_n1);
        BARR(); LGKM0(); QUAD(1, 1); VMC4(); BARR();
        k0 += 128;
    }
    asm volatile("s_waitcnt vmcnt(0)" ::: "memory");

    // ---- epilogue: m = m0 + wm*128 + mf*16 + quad*4 + rr,
    //                n = n0 + wn*64 + nf*16 + l15
    float bb[4];
#pragma unroll
    for (int nf = 0; nf < 4; ++nf) bb[nf] = bias[n0 + wn * 64 + nf * 16 + l15];
#pragma unroll
    for (int mf = 0; mf < 8; ++mf)
#pragma unroll
        for (int nf = 0; nf < 4; ++nf)
#pragma unroll
            for (int rr = 0; rr < 4; ++rr) acc[mf][nf][rr] += bb[nf];

    {  // O-proj fp32 row-major
        float* O = (float*)Cp;
#pragma unroll
        for (int mf = 0; mf < 8; ++mf) {
#pragma unroll
            for (int rr = 0; rr < 4; ++rr) {
                const int m = m0 + wm * 128 + mf * 16 + quad * 4 + rr;
#pragma unroll
                for (int nf = 0; nf < 4; ++nf)
                    O[(size_t)m * 1024 + n0 + wn * 64 + nf * 16 + l15] =
                        acc[mf][nf][rr];
            }
        }
    }
    (void)nfp;
#undef STAGE
#undef LDA4
#undef LDB2
#undef QUAD
#undef FENCE
#undef BARR
#undef LGKM0
#undef VMC4
}

// ---------------------------------------------------------------------------
// 8-phase 256x256 Q-proj GEMM with fp32 A (raw patches) converted in-kernel.
// B (WqT fp16) stays on the global_load_lds path; A uses T14 reg-staging:
//   LDAG: 4x global_load_dwordx4 (fp32) -> 16 floats in a named slot
//   STAW: (compiler-auto vmcnt) cvt 16 -> f16, 2x ds_write_b128, swizzled
// Ledger (buf0=t0, buf1=t1; consumers same as gemm8p):
//   P0: rd A0[0-3]+B0[0-1] | stB B1h1(t1)  | LDAG sx<-A1h1(t1)
//   P1: rd B0[2-3]
//   P2: rd A0[4-7]         | stB B0h0(t0+2)| STAW sx->A1h1
//   P3:                    | stB B0h1(t0+2)| LDAG sy<-A0h0(t0+2)
//   P4: rd A1[0-3]+B1[0-1]
//   P5: rd B1[2-3]         | STAW sy->A0h0 | LDAG sy<-A0h1(t0+2)
//   P6: rd A1[4-7]         | stB B1h0(t1+2)| STAW sy->A0h1 | LDAG sx<-A1h0(t1+2)
//   P7:                    | STAW sx->A1h0
// No manual vmcnt needed: each STAW's compiler-inserted vmcnt (FIFO) drains
// every older stB before its consumer phase (checked per stage above).  Each
// STAW writes a half whose last ds_read was >=1 phase earlier; each consumer
// crosses a barrier the writer reached after its lgkmcnt(0) drain.
// ---------------------------------------------------------------------------
__global__ __launch_bounds__(512, 2) void gemm8q(const float* __restrict__ Af,
                                                 const _Float16* __restrict__ BT,
                                                 const float* __restrict__ bias,
                                                 _Float16* __restrict__ O,
                                                 const int* __restrict__ nfp) {
    constexpr int K = 1024;
    __shared__ alignas(16) _Float16 lds[2][2][2][128 * 64];  // [buf][A=0/B=1][half]

    const int tid = threadIdx.x;
    const int lane = tid & 63, quad = lane >> 4, l15 = lane & 15;
    const int w = tid >> 6, wm = w >> 2, wn = w & 3;

    int lin = blockIdx.x;
    lin = (lin & 7) * 32 + (lin >> 3);
    const int m0 = (lin >> 2) * 256;
    const int n0 = (lin & 3) * 256;

    f32x4 acc[8][4];
#pragma unroll
    for (int mf = 0; mf < 8; ++mf)
#pragma unroll
        for (int nf = 0; nf < 4; ++nf)
#pragma unroll
            for (int rr = 0; rr < 4; ++rr) acc[mf][nf][rr] = 0.f;

    f16x8 ra[4][2], rb[4][2];
    float4 sxa[2], sxb[2], sya[2], syb[2];

#define STB(BUF, HALF, KK0)                                                     \
    {                                                                           \
        _Float16* dst_ = &lds[BUF][1][HALF][0];                                 \
        _Pragma("unroll") for (int i_ = 0; i_ < 2; ++i_) {                      \
            const int id_ = i_ * 512 + tid;                                     \
            const int r_ = id_ >> 3;                                            \
            const int c_ = (id_ & 7) ^ (r_ & 7);                                \
            async_cp16(BT + (size_t)(n0 + (HALF) * 128 + r_) * K + (KK0) + c_ * 8, \
                       dst_ + i_ * 4096 + w * 512);                             \
        }                                                                       \
    }

#define LDAG(SL, HALF, KK0)                                                     \
    _Pragma("unroll") for (int i_ = 0; i_ < 2; ++i_) {                          \
        const int id_ = i_ * 512 + tid;                                         \
        const int r_ = id_ >> 3;                                                \
        const int c_ = (id_ & 7) ^ (r_ & 7);                                    \
        const float4* src_ = (const float4*)&Af[(size_t)(m0 + (HALF) * 128 + r_) * 1024 + (KK0) + c_ * 8]; \
        SL##a[i_] = src_[0];                                                    \
        SL##b[i_] = src_[1];                                                    \
    }

#define STAW(BUF, HALF, SL)                                                     \
    _Pragma("unroll") for (int i_ = 0; i_ < 2; ++i_) {                          \
        const int id_ = i_ * 512 + tid;                                         \
        const int r_ = id_ >> 3;                                                \
        const int s_ = id_ & 7;                                                 \
        f16x8 h_;                                                               \
        h_[0] = (_Float16)SL##a[i_].x; h_[1] = (_Float16)SL##a[i_].y;           \
        h_[2] = (_Float16)SL##a[i_].z; h_[3] = (_Float16)SL##a[i_].w;           \
        h_[4] = (_Float16)SL##b[i_].x; h_[5] = (_Float16)SL##b[i_].y;           \
        h_[6] = (_Float16)SL##b[i_].z; h_[7] = (_Float16)SL##b[i_].w;           \
        *(f16x8*)&lds[BUF][0][HALF][r_ * 64 + s_ * 8] = h_;                     \
    }

#define LDA4(BUF, MH)                                                           \
    _Pragma("unroll") for (int i_ = 0; i_ < 4; ++i_)                            \
    _Pragma("unroll") for (int ks_ = 0; ks_ < 2; ++ks_) {                       \
        const int row_ = ((MH) * 4 + i_) * 16 + l15;                            \
        ra[i_][ks_] = *(const f16x8*)&lds[BUF][0][wm]                           \
            [row_ * 64 + (((ks_ * 4 + quad) ^ (l15 & 7)) * 8)];                 \
    }

#define LDB2(BUF, NFROM)                                                        \
    _Pragma("unroll") for (int j_ = 0; j_ < 2; ++j_)                            \
    _Pragma("unroll") for (int ks_ = 0; ks_ < 2; ++ks_) {                       \
        const int nf_ = (NFROM) + j_;                                           \
        const int row_ = (wn & 1) * 64 + nf_ * 16 + l15;                        \
        rb[nf_][ks_] = *(const f16x8*)&lds[BUF][1][wn >> 1]                     \
            [row_ * 64 + (((ks_ * 4 + quad) ^ (l15 & 7)) * 8)];                 \
    }

#define QUAD(QM, QN)                                                            \
    {                                                                           \
        __builtin_amdgcn_s_setprio(1);                                          \
        _Pragma("unroll") for (int i_ = 0; i_ < 4; ++i_)                        \
        _Pragma("unroll") for (int j_ = 0; j_ < 2; ++j_)                        \
        _Pragma("unroll") for (int ks_ = 0; ks_ < 2; ++ks_)                     \
            acc[(QM) * 4 + i_][(QN) * 2 + j_] =                                 \
                MFMA16(ra[i_][ks_], rb[(QN) * 2 + j_][ks_],                     \
                       acc[(QM) * 4 + i_][(QN) * 2 + j_]);                      \
        __builtin_amdgcn_s_setprio(0);                                          \
    }

#define FENCE() asm volatile("" ::: "memory")
#define BARR()  FENCE(); __builtin_amdgcn_s_barrier(); FENCE()
#define LGKM0() asm volatile("s_waitcnt lgkmcnt(0)" ::: "memory");              \
                __builtin_amdgcn_sched_barrier(0)

    // prologue: B0h0,B0h1,B1h0 via gload_lds; A0h0,A0h1,A1h0 via reg-path
    STB(0, 0, 0);
    STB(0, 1, 0);
    STB(1, 0, 64);
    LDAG(sx, 0, 0);
    LDAG(sy, 1, 0);
    STAW(0, 0, sx);   // auto-vmcnt drains the 3 stB too
    STAW(0, 1, sy);
    LDAG(sx, 0, 64);
    STAW(1, 0, sx);
    LGKM0();
    BARR();

    int k0 = 0;
#pragma unroll 1
    for (int it = 0; it < 8; ++it) {
        const int k_t1 = k0 + 64;
        const int k_n0 = (k0 + 128 < K) ? k0 + 128 : K - 64;
        const int k_n1 = (k0 + 192 < K) ? k0 + 192 : K - 64;
        // P0
        LDA4(0, 0); LDB2(0, 0);
        STB(1, 1, k_t1);
        LDAG(sx, 1, k_t1);
        BARR(); LGKM0(); QUAD(0, 0); BARR();
        // P1
        LDB2(0, 2);
        BARR(); LGKM0(); QUAD(0, 1); BARR();
        // P2
        LDA4(0, 1);
        STB(0, 0, k_n0);
        STAW(1, 1, sx);
        BARR(); LGKM0(); QUAD(1, 0); BARR();
        // P3
        STB(0, 1, k_n0);
        LDAG(sy, 0, k_n0);
        BARR(); LGKM0(); QUAD(1, 1); BARR();
        // P4
        LDA4(1, 0); LDB2(1, 0);
        BARR(); LGKM0(); QUAD(0, 0); BARR();
        // P5
        LDB2(1, 2);
        STAW(0, 0, sy);
        LDAG(sy, 1, k_n0);
        BARR(); LGKM0(); QUAD(0, 1); BARR();
        // P6
        LDA4(1, 1);
        STB(1, 0, k_n1);
        STAW(0, 1, sy);
        LDAG(sx, 0, k_n1);
        BARR(); LGKM0(); QUAD(1, 0); BARR();
        // P7
        STAW(1, 0, sx);
        BARR(); LGKM0(); QUAD(1, 1); BARR();
        k0 += 128;
    }
    asm volatile("s_waitcnt vmcnt(0) lgkmcnt(0)" ::: "memory");

    // ---- Q epilogue: bias + RoPE + *0.125 -> q_h[b][h][lq][hd] fp16
    const int nf_frames = nfp[0];
    float bb[4];
#pragma unroll
    for (int nf = 0; nf < 4; ++nf) bb[nf] = bias[n0 + wn * 64 + nf * 16 + l15];
#pragma unroll
    for (int mf = 0; mf < 8; ++mf)
#pragma unroll
        for (int nf = 0; nf < 4; ++nf)
#pragma unroll
            for (int rr = 0; rr < 4; ++rr) acc[mf][nf][rr] += bb[nf];

    const float l2b = 13.287712379549449f;
    const float inv0 = exp2f(-((float)l15 * (1.0f / 32.0f)) * l2b);
    const float inv1 = exp2f(-((float)(16 + l15) * (1.0f / 32.0f)) * l2b);
    const int head = (n0 + wn * 64) >> 6;
    // sincos hoist: pos = lq/dv is constant across the wave-half's 128 rows
    // whenever they fall in one frame bucket (true for nf_frames <= 32).
    int dv = 4096;
    bool uni = false;
    float us0 = 0.f, uc0 = 1.f, us1 = 0.f, uc1 = 1.f;
    if (nf_frames > 1) {
        dv = 4096 / nf_frames;
        const int lqb = (m0 + wm * 128) & 4095;
        uni = (lqb / dv) == ((lqb + 127) / dv);
        if (uni) {
            const float fp = (float)(lqb / dv);
            __sincosf(fp * inv0, &us0, &uc0);
            __sincosf(fp * inv1, &us1, &uc1);
        }
    }
#pragma unroll
    for (int mf = 0; mf < 8; ++mf) {
#pragma unroll
        for (int rr = 0; rr < 4; ++rr) {
            const int m = m0 + wm * 128 + mf * 16 + quad * 4 + rr;
            const int b = m >> 12, lq = m & 4095;
            if (nf_frames > 1) {
                float s0, c0, s1, c1;
                if (uni) {
                    s0 = us0; c0 = uc0; s1 = us1; c1 = uc1;
                } else {
                    const int pos = lq / dv;
                    __sincosf((float)pos * inv0, &s0, &c0);
                    __sincosf((float)pos * inv1, &s1, &c1);
                }
                const float x0 = acc[mf][0][rr], x2 = acc[mf][2][rr];
                const float x1 = acc[mf][1][rr], x3 = acc[mf][3][rr];
                acc[mf][0][rr] = x0 * c0 - x2 * s0;
                acc[mf][2][rr] = x2 * c0 + x0 * s0;
                acc[mf][1][rr] = x1 * c1 - x3 * s1;
                acc[mf][3][rr] = x3 * c1 + x1 * s1;
            }
            const size_t base = (((size_t)(b * 16 + head)) * 4096 + lq) * 64;
#pragma unroll
            for (int nf = 0; nf < 4; ++nf)
                O[base + nf * 16 + l15] = (_Float16)(acc[mf][nf][rr] * 0.125f);
        }
    }
#undef STB
#undef LDAG
#undef STAW
#undef LDA4
#undef LDB2
#undef QUAD
#undef FENCE
#undef BARR
#undef LGKM0
}

// ---------------------------------------------------------------------------
// Attention v6.  Block = 8 waves = 512 q-rows of one (b,h); wave = 4 chunks
// of 16 q-rows.  K and V_pi staged in LDS (32 KB each, 16B-chunk XOR
// swizzles), Q prefetched one chunk ahead, per-wave chunk rotation.
// ---------------------------------------------------------------------------
__global__ __launch_bounds__(512, 4) void attn5(const _Float16* __restrict__ qh,
                                                const _Float16* __restrict__ kh,
                                                const _Float16* __restrict__ vp,
                                                _Float16* __restrict__ attn) {
    __shared__ _Float16 Ks[256 * 64];  // swizzled: chunk c of row r at c^(r&7)
    __shared__ _Float16 Vs[64 * 256];  // swizzled: chunk s of row hd at s^((hd&7)<<2)

    const int tid = threadIdx.x;
    const int w = tid >> 6, lane = tid & 63, quad = lane >> 4, l15 = lane & 15;
    const int bh = blockIdx.x, b = bh >> 4, h = bh & 15, kvh = h >> 2;
    const int q0 = blockIdx.y * 512;

    const _Float16* kb = kh + (size_t)(b * 4 + kvh) * 256 * 64;
    const _Float16* vb = vp + (size_t)(b * 4 + kvh) * 64 * 256;
    const _Float16* qb = qh + ((size_t)bh * 4096 + q0) * 64;

    // ---- stage K into LDS (2048 x 16B chunks, 4/thread), source-swizzled
#pragma unroll
    for (int i = 0; i < 4; ++i) {
        const int id = i * 512 + tid;
        const int r = id >> 3;
        const int c = (id & 7) ^ (r & 7);
        async_cp16(kb + (size_t)r * 64 + c * 8, Ks + i * 4096 + w * 512);
    }
    // ---- stage V_pi into LDS (2048 x 16B chunks), source-swizzled
#pragma unroll
    for (int i = 0; i < 4; ++i) {
        const int id = i * 512 + tid;
        const int hd = id >> 5;
        const int s5 = id & 31;
        const int c = s5 ^ ((hd & 7) << 2);
        async_cp16(vb + (size_t)hd * 256 + c * 8, Vs + i * 4096 + w * 512);
    }
    __syncthreads();

    const int sw = l15 & 7;        // K read-side swizzle key (row&7 == l15&7)
    const int p0 = quad ^ sw;      // slot of k-chunk quad (hd 0..31)
    const int vsw = sw << 2;       // V read-side swizzle key (hd&7 == l15&7)
    const int crot = w & 3;        // per-wave chunk rotation (de-convoy)

    // prefetch Q for first chunk
    const _Float16* qpre = qb + (size_t)(w * 64 + crot * 16 + l15) * 64 + quad * 8;
    f16x8 bq0 = *(const f16x8*)qpre;
    f16x8 bq1 = *(const f16x8*)(qpre + 32);

#pragma unroll 1
    for (int cc = 0; cc < 4; ++cc) {
        const int chunk = (cc + crot) & 3;
        const int qrow = w * 64 + chunk * 16;

        // issue next chunk's Q loads now; consumed next iteration
        const int nchunk = (cc + 1 + crot) & 3;
        const _Float16* np = qb + (size_t)(w * 64 + nchunk * 16 + l15) * 64 + quad * 8;
        const f16x8 nq0 = *(const f16x8*)np;
        const f16x8 nq1 = *(const f16x8*)(np + 32);

        // S^T = K @ Q^T : lane holds S[q=l15][kv = t*16 + quad*4 + rr]
        f32x4 st[16];
#pragma unroll
        for (int t = 0; t < 16; ++t)
#pragma unroll
            for (int rr = 0; rr < 4; ++rr) st[t][rr] = 0.f;

#pragma unroll
        for (int t = 0; t < 16; ++t) {
            const int row = t * 16 + l15;
            const f16x8 ka0 = *(const f16x8*)&Ks[row * 64 + p0 * 8];
            const f16x8 ka1 = *(const f16x8*)&Ks[row * 64 + (p0 ^ 4) * 8];
            st[t] = MFMA16(ka0, bq0, st[t]);
            st[t] = MFMA16(ka1, bq1, st[t]);
        }

        // softmax over 256 kv (row q = l15 -> 2 shuffles)
        float rm = -1e30f;
#pragma unroll
        for (int t = 0; t < 16; ++t)
#pragma unroll
            for (int rr = 0; rr < 4; ++rr) rm = fmaxf(rm, st[t][rr]);
        rm = fmaxf(rm, __shfl_xor(rm, 16, 64));
        rm = fmaxf(rm, __shfl_xor(rm, 32, 64));

        float rs = 0.f;
#pragma unroll
        for (int t = 0; t < 16; ++t) {
#pragma unroll
            for (int rr = 0; rr < 4; ++rr) {
                st[t][rr] = __expf(st[t][rr] - rm);
                rs += st[t][rr];
            }
        }
        rs += __shfl_xor(rs, 16, 64);
        rs += __shfl_xor(rs, 32, 64);
        const float ir = 1.0f / rs;  // per-lane correct for q = l15

        // opaque 0 offset: keep the 32 V ds_reads inside this iteration
        int vo = 0;
        asm volatile("" : "+v"(vo));

        // O^T = V_pi @ P^T : 4 hd-tiles, k = 256 in 8 chunks of 32
        f32x4 o[4];
#pragma unroll
        for (int nt = 0; nt < 4; ++nt)
#pragma unroll
            for (int rr = 0; rr < 4; ++rr) o[nt][rr] = 0.f;

#pragma unroll
        for (int c = 0; c < 8; ++c) {
            // P^T B-frag: slot (quad, j) <-> kv = 32c + 16*(j>>2) + 4*quad + (j&3)
            f16x8 pb;
#pragma unroll
            for (int j = 0; j < 8; ++j)
                pb[j] = (_Float16)st[2 * c + (j >> 2)][j & 3];
#pragma unroll
            for (int nt = 0; nt < 4; ++nt) {
                const f16x8 va = *(const f16x8*)&Vs[(nt * 16 + l15) * 256 +
                                                   (((c * 4 + quad) ^ vsw) * 8) + vo];
                o[nt] = MFMA16(va, pb, o[nt]);
            }
        }

        // store: O^T C-frag: q = l15, hd = nt*16 + quad*4 + rr -> f16x4 packs
        const size_t rowbase = ((size_t)b * 4096 + q0 + qrow + l15) * 1024 + h * 64;
#pragma unroll
        for (int nt = 0; nt < 4; ++nt) {
            f16x4 ov;
#pragma unroll
            for (int rr = 0; rr < 4; ++rr) ov[rr] = (_Float16)(o[nt][rr] * ir);
            *(f16x4*)&attn[rowbase + nt * 16 + quad * 4] = ov;
        }

        bq0 = nq0; bq1 = nq1;
    }
}

// ---------------------------------------------------------------------------
extern "C" void kernel_launch(void* const* d_in, const int* in_sizes, int n_in,
                              void* d_out, int out_size, void* d_ws, size_t ws_size,
                              hipStream_t stream) {
    const float* patches = (const float*)d_in[0];
    const float* latents = (const float*)d_in[1];
    const float* Wq = (const float*)d_in[2];
    const float* bq = (const float*)d_in[3];
    const float* Wk = (const float*)d_in[4];
    const float* bk = (const float*)d_in[5];
    const float* Wv = (const float*)d_in[6];
    const float* bv = (const float*)d_in[7];
    const float* Wo = (const float*)d_in[8];
    const float* bo = (const float*)d_in[9];
    const int*   nf = (const int*)d_in[10];
    float* out = (float*)d_out;
    (void)in_sizes; (void)n_in; (void)out_size; (void)ws_size;

    char* p = (char*)d_ws;
    _Float16* WqT  = (_Float16*)p; p += (size_t)1024 * 1024 * 2;
    _Float16* WkvT = (_Float16*)p; p += (size_t)512 * 1024 * 2;
    _Float16* WoT  = (_Float16*)p; p += (size_t)1024 * 1024 * 2;
    float*    bkv  = (float*)p;    p += 4096;
    _Float16* l16  = (_Float16*)p; p += (size_t)4 * 256 * 1024 * 2;
    _Float16* q_h  = (_Float16*)p; p += (size_t)4 * 16 * 4096 * 64 * 2;
    _Float16* k_h  = (_Float16*)p; p += (size_t)4 * 4 * 256 * 64 * 2;
    _Float16* v_pi = (_Float16*)p; p += (size_t)4 * 4 * 256 * 64 * 2;  // after k_h
    _Float16* attn_h = (_Float16*)p; p += (size_t)16384 * 1024 * 2;

    transpose_all<<<dim3(16, 16, 4), 256, 0, stream>>>(Wq, Wk, Wv, Wo, WqT, WkvT, WoT);
    cvt_lat<<<1024, 256, 0, stream>>>((const float4*)latents, (f16x4*)l16);
    catbias<<<1, 512, 0, stream>>>(bk, bv, bkv);

    gemm32<1><<<dim3(4, 4), 256, 0, stream>>>(l16, WkvT, bkv, k_h, nf);
    gemm8q<<<256, 512, 0, stream>>>(patches, WqT, bq, q_h, nf);

    attn5<<<dim3(64, 8), 512, 0, stream>>>(q_h, k_h, v_pi, attn_h);

    gemm8p<2><<<256, 512, 0, stream>>>(attn_h, WoT, bo, out, nf);
}

// Round 5
// 283.994 us; speedup vs baseline: 1.0886x; 1.0886x over previous
//
#include <hip/hip_runtime.h>
#include <hip/hip_fp16.h>
#include <cstdint>

typedef _Float16 f16x8 __attribute__((ext_vector_type(8)));
typedef _Float16 f16x4 __attribute__((ext_vector_type(4)));
typedef __fp16   fp16x2 __attribute__((ext_vector_type(2)));  // cvt_pkrtz return type
typedef float    f32x4 __attribute__((ext_vector_type(4)));
typedef float    f32x16 __attribute__((ext_vector_type(16)));

#define MFMA16(a, b, c) __builtin_amdgcn_mfma_f32_16x16x32_f16((a), (b), (c), 0, 0, 0)
#define MFMA32(a, b, c) __builtin_amdgcn_mfma_f32_32x32x16_f16((a), (b), (c), 0, 0, 0)

// B=4, LQ=4096, LKV=256, D=1024, H=16, KVH=4, HD=64

__device__ __forceinline__ void async_cp16(const _Float16* g, _Float16* l) {
    __builtin_amdgcn_global_load_lds(
        (const __attribute__((address_space(1))) void*)g,
        (__attribute__((address_space(3))) void*)l, 16, 0, 0);
}

// ---------------------------------------------------------------------------
// prep: ONE launch fusing (a) fp32->fp16 convert of patches+latents,
// (b) all 4 weight transposes, (c) bkv concat.  No mutual deps; flat grid.
//   blocks [0, 17408)          : cvt (256 float4 each)
//   blocks [17408, 18432)      : transpose tiles (z = t>>8, 64x64 tile)
//   block  18432               : catbias
// ---------------------------------------------------------------------------
__global__ __launch_bounds__(256) void prep(
    const float4* __restrict__ patches, const float4* __restrict__ latents,
    f16x4* __restrict__ p16, f16x4* __restrict__ l16,
    const float* __restrict__ Wq, const float* __restrict__ Wk,
    const float* __restrict__ Wv, const float* __restrict__ Wo,
    _Float16* __restrict__ WqT, _Float16* __restrict__ WkvT,
    _Float16* __restrict__ WoT,
    const float* __restrict__ bk, const float* __restrict__ bv,
    float* __restrict__ bkv) {
    __shared__ float T[64][65];
    const int tid = threadIdx.x;
    const int bid = blockIdx.x;

    if (bid < 17408) {  // cvt
        const long i = (long)bid * 256 + tid;
        const float4 v = (i < 4194304) ? patches[i] : latents[i - 4194304];
        f16x4 o;
        o[0] = (_Float16)v.x; o[1] = (_Float16)v.y;
        o[2] = (_Float16)v.z; o[3] = (_Float16)v.w;
        if (i < 4194304) p16[i] = o; else l16[i - 4194304] = o;
        return;
    }
    if (bid == 18432) {  // catbias
        bkv[tid] = bk[tid];
        bkv[256 + tid] = bv[tid];
        return;
    }
    // transpose: fp32 [K][N] -> fp16 [N][K]
    const int t = bid - 17408;
    const int z = t >> 8, rem = t & 255, xb = rem & 15, yb = rem >> 4;
    const float* W;
    _Float16* WT;
    int Nd;
    if (z == 0)      { W = Wq; WT = WqT;                       Nd = 1024; }
    else if (z == 1) { W = Wk; WT = WkvT;                      Nd = 256;  }
    else if (z == 2) { W = Wv; WT = WkvT + (size_t)256 * 1024; Nd = 256;  }
    else             { W = Wo; WT = WoT;                       Nd = 1024; }
    const int n0 = xb * 64, k0 = yb * 64;
    if (n0 >= Nd) return;

    const int nl = tid & 63, kg = tid >> 6;
#pragma unroll
    for (int i = 0; i < 16; ++i) {
        const int kl = kg * 16 + i;
        T[kl][nl] = W[(size_t)(k0 + kl) * Nd + n0 + nl];
    }
    __syncthreads();
    const int kl = tid & 63;
#pragma unroll
    for (int i = 0; i < 16; ++i) {
        const int nl2 = kg * 16 + i;
        WT[(size_t)(n0 + nl2) * 1024 + k0 + kl] = (_Float16)T[kl][nl2];
    }
}

// ---------------------------------------------------------------------------
// Small-M GEMM (KV-proj only): 2-barrier structure, 256x128 tile.
// ---------------------------------------------------------------------------
template <int EPI>
__global__ __launch_bounds__(256, 2) void gemm32(const _Float16* __restrict__ A,
                                                 const _Float16* __restrict__ BT,
                                                 const float* __restrict__ bias,
                                                 void* __restrict__ Cp,
                                                 const int* __restrict__ nfp) {
    constexpr int K = 1024;
    __shared__ _Float16 As[256 * 64];
    __shared__ _Float16 Bs[128 * 64];

    const int tid = threadIdx.x;
    const int lane = tid & 63, l31 = lane & 31, hh = lane >> 5;
    const int w = tid >> 6, wm = w >> 1, wn = w & 1;

    const int n0 = blockIdx.x * 128;
    const int m0 = blockIdx.y * 256;

    f32x16 acc[4][2];
#pragma unroll
    for (int mt = 0; mt < 4; ++mt)
#pragma unroll
        for (int nt = 0; nt < 2; ++nt)
#pragma unroll
            for (int v = 0; v < 16; ++v) acc[mt][nt][v] = 0.f;

    for (int k0 = 0; k0 < K; k0 += 64) {
#pragma unroll
        for (int i = 0; i < 8; ++i) {
            const int id = i * 256 + tid;
            const int r = id >> 3;
            const int c = (id & 7) ^ (r & 7);
            async_cp16(A + (size_t)(m0 + r) * K + k0 + c * 8,
                       As + i * 2048 + w * 512);
        }
#pragma unroll
        for (int i = 0; i < 4; ++i) {
            const int id = i * 256 + tid;
            const int r = id >> 3;
            const int c = (id & 7) ^ (r & 7);
            async_cp16(BT + (size_t)(n0 + r) * K + k0 + c * 8,
                       Bs + i * 2048 + w * 512);
        }
        __syncthreads();

#pragma unroll
        for (int kk = 0; kk < 4; ++kk) {
            f16x8 af[4], bf[2];
#pragma unroll
            for (int mt = 0; mt < 4; ++mt) {
                const int row = wm * 128 + mt * 32 + l31;
                const int pc = (kk * 2 + hh) ^ (row & 7);
                af[mt] = *(const f16x8*)&As[row * 64 + pc * 8];
            }
#pragma unroll
            for (int nt = 0; nt < 2; ++nt) {
                const int row = wn * 64 + nt * 32 + l31;
                const int pc = (kk * 2 + hh) ^ (row & 7);
                bf[nt] = *(const f16x8*)&Bs[row * 64 + pc * 8];
            }
#pragma unroll
            for (int mt = 0; mt < 4; ++mt)
#pragma unroll
                for (int nt = 0; nt < 2; ++nt)
                    acc[mt][nt] = MFMA32(af[mt], bf[nt], acc[mt][nt]);
        }
        __syncthreads();
    }

    const int nf = nfp[0];
    const int nbase = n0 + wn * 64;

    float bb[2];
#pragma unroll
    for (int nt = 0; nt < 2; ++nt) bb[nt] = bias[nbase + nt * 32 + l31];
#pragma unroll
    for (int mt = 0; mt < 4; ++mt)
#pragma unroll
        for (int nt = 0; nt < 2; ++nt)
#pragma unroll
            for (int v = 0; v < 16; ++v) acc[mt][nt][v] += bb[nt];

    {  // K/V fused (N=512)
        _Float16* kout = (_Float16*)Cp;
        _Float16* vout = kout + (size_t)4 * 4 * 256 * 64;
        if (nbase < 256) {
            const float l2b = 13.287712379549449f;
            const float inv = exp2f(-((float)l31 * (1.0f / 32.0f)) * l2b);
            const int dv = 256 / (nf > 1 ? nf : 1);
            const int kvh = nbase >> 6;
#pragma unroll
            for (int mt = 0; mt < 4; ++mt) {
#pragma unroll
                for (int v = 0; v < 16; ++v) {
                    const int m = m0 + wm * 128 + mt * 32 + (v & 3) + 8 * (v >> 2) + 4 * hh;
                    const int b = m >> 8, lkv = m & 255;
                    if (nf > 1) {
                        const int pos = lkv / dv;
                        float s, c;
                        __sincosf((float)pos * inv, &s, &c);
                        const float x1 = acc[mt][0][v], x2 = acc[mt][1][v];
                        acc[mt][0][v] = x1 * c - x2 * s;
                        acc[mt][1][v] = x2 * c + x1 * s;
                    }
#pragma unroll
                    for (int nt = 0; nt < 2; ++nt) {
                        const int hd = nt * 32 + l31;
                        kout[(((size_t)(b * 4 + kvh)) * 256 + lkv) * 64 + hd] =
                            (_Float16)acc[mt][nt][v];
                    }
                }
            }
        } else {
            const int kvh = (nbase - 256) >> 6;
#pragma unroll
            for (int mt = 0; mt < 4; ++mt) {
#pragma unroll
                for (int v = 0; v < 16; ++v) {
                    const int m = m0 + wm * 128 + mt * 32 + (v & 3) + 8 * (v >> 2) + 4 * hh;
                    const int b = m >> 8, lkv = m & 255;
                    // pi-permuted kv slot: swap the 16s bit below the 4s bits
                    const int s = (lkv & 0xE0) | ((lkv & 12) << 1) |
                                  ((lkv & 16) >> 2) | (lkv & 3);
#pragma unroll
                    for (int nt = 0; nt < 2; ++nt) {
                        const int hd = nt * 32 + l31;
                        vout[(((size_t)(b * 4 + kvh)) * 64 + hd) * 256 + s] =
                            (_Float16)acc[mt][nt][v];
                    }
                }
            }
        }
    }
}

// ---------------------------------------------------------------------------
// 8-phase 256x256 GEMM (T2+T3+T4+T5), round-2 structure (measured 44 us,
// MfmaUtil 30%, 0 bank conflicts).  EPI 0: Q-proj (bias+RoPE, scale folds
// log2e/8 so attn can use exp2 directly).  EPI 2: O-proj (fp32).
// ---------------------------------------------------------------------------
template <int EPI>
__global__ __launch_bounds__(512, 2) void gemm8p(const _Float16* __restrict__ A,
                                                 const _Float16* __restrict__ BT,
                                                 const float* __restrict__ bias,
                                                 void* __restrict__ Cp,
                                                 const int* __restrict__ nfp) {
    constexpr int K = 1024;
    __shared__ alignas(16) _Float16 lds[2][2][2][128 * 64];  // [buf][A=0/B=1][half]

    const int tid = threadIdx.x;
    const int lane = tid & 63, quad = lane >> 4, l15 = lane & 15;
    const int w = tid >> 6, wm = w >> 2, wn = w & 3;

    // bijective XCD swizzle: 256 blocks, 8 XCDs -> 32-block m-stripes
    int lin = blockIdx.x;
    lin = (lin & 7) * 32 + (lin >> 3);
    const int m0 = (lin >> 2) * 256;
    const int n0 = (lin & 3) * 256;

    f32x4 acc[8][4];
#pragma unroll
    for (int mf = 0; mf < 8; ++mf)
#pragma unroll
        for (int nf = 0; nf < 4; ++nf)
#pragma unroll
            for (int rr = 0; rr < 4; ++rr) acc[mf][nf][rr] = 0.f;

    f16x8 ra[4][2], rb[4][2];

#define STAGE(BUF, MAT, HALF, KK0)                                              \
    {                                                                           \
        const _Float16* g_ = (MAT) ? BT : A;                                    \
        const int rb_ = ((MAT) ? n0 : m0) + (HALF) * 128;                       \
        _Float16* dst_ = &lds[BUF][MAT][HALF][0];                               \
        _Pragma("unroll") for (int i_ = 0; i_ < 2; ++i_) {                      \
            const int id_ = i_ * 512 + tid;                                     \
            const int r_ = id_ >> 3;                                            \
            const int c_ = (id_ & 7) ^ (r_ & 7);                                \
            async_cp16(g_ + (size_t)(rb_ + r_) * K + (KK0) + c_ * 8,            \
                       dst_ + i_ * 4096 + w * 512);                             \
        }                                                                       \
    }

#define LDA4(BUF, MH)                                                           \
    _Pragma("unroll") for (int i_ = 0; i_ < 4; ++i_)                            \
    _Pragma("unroll") for (int ks_ = 0; ks_ < 2; ++ks_) {                       \
        const int row_ = ((MH) * 4 + i_) * 16 + l15;                            \
        ra[i_][ks_] = *(const f16x8*)&lds[BUF][0][wm]                           \
            [row_ * 64 + (((ks_ * 4 + quad) ^ (l15 & 7)) * 8)];                 \
    }

#define LDB2(BUF, NFROM)                                                        \
    _Pragma("unroll") for (int j_ = 0; j_ < 2; ++j_)                            \
    _Pragma("unroll") for (int ks_ = 0; ks_ < 2; ++ks_) {                       \
        const int nf_ = (NFROM) + j_;                                           \
        const int row_ = (wn & 1) * 64 + nf_ * 16 + l15;                        \
        rb[nf_][ks_] = *(const f16x8*)&lds[BUF][1][wn >> 1]                     \
            [row_ * 64 + (((ks_ * 4 + quad) ^ (l15 & 7)) * 8)];                 \
    }

#define QUAD(QM, QN)                                                            \
    {                                                                           \
        __builtin_amdgcn_s_setprio(1);                                          \
        _Pragma("unroll") for (int i_ = 0; i_ < 4; ++i_)                        \
        _Pragma("unroll") for (int j_ = 0; j_ < 2; ++j_)                        \
        _Pragma("unroll") for (int ks_ = 0; ks_ < 2; ++ks_)                     \
            acc[(QM) * 4 + i_][(QN) * 2 + j_] =                                 \
                MFMA16(ra[i_][ks_], rb[(QN) * 2 + j_][ks_],                     \
                       acc[(QM) * 4 + i_][(QN) * 2 + j_]);                      \
        __builtin_amdgcn_s_setprio(0);                                          \
    }

#define FENCE() asm volatile("" ::: "memory")
#define BARR()  FENCE(); __builtin_amdgcn_s_barrier(); FENCE()
#define LGKM0() asm volatile("s_waitcnt lgkmcnt(0)" ::: "memory");              \
                __builtin_amdgcn_sched_barrier(0)
#define VMC4()  asm volatile("s_waitcnt vmcnt(4)" ::: "memory")

    // prologue: tile0 (all 4 halves) + tile1 (B0, A0)
    STAGE(0, 1, 0, 0);
    STAGE(0, 1, 1, 0);
    STAGE(0, 0, 0, 0);
    STAGE(0, 0, 1, 0);
    STAGE(1, 1, 0, 64);
    STAGE(1, 0, 0, 64);
    VMC4();
    BARR();

    int k0 = 0;
#pragma unroll 1
    for (int it = 0; it < 8; ++it) {
        const int k_t1 = k0 + 64;
        const int k_n0 = (k0 + 128 < K) ? k0 + 128 : K - 64;  // tile t0+2
        const int k_n1 = (k0 + 192 < K) ? k0 + 192 : K - 64;  // tile t1+2
        // P0
        LDA4(0, 0); LDB2(0, 0);
        STAGE(1, 1, 1, k_t1);
        BARR(); LGKM0(); QUAD(0, 0); BARR();
        // P1
        LDB2(0, 2);
        STAGE(1, 0, 1, k_t1);
        BARR(); LGKM0(); QUAD(0, 1); BARR();
        // P2
        LDA4(0, 1);
        STAGE(0, 1, 0, k_n0);
        BARR(); LGKM0(); QUAD(1, 0); BARR();
        // P3
        STAGE(0, 1, 1, k_n0);
        BARR(); LGKM0(); QUAD(1, 1); VMC4(); BARR();
        // P4
        LDA4(1, 0); LDB2(1, 0);
        STAGE(0, 0, 0, k_n0);
        BARR(); LGKM0(); QUAD(0, 0); BARR();
        // P5
        LDB2(1, 2);
        STAGE(0, 0, 1, k_n0);
        BARR(); LGKM0(); QUAD(0, 1); BARR();
        // P6
        LDA4(1, 1);
        STAGE(1, 1, 0, k_n1);
        BARR(); LGKM0(); QUAD(1, 0); BARR();
        // P7
        STAGE(1, 0, 0, k_n1);
        BARR(); LGKM0(); QUAD(1, 1); VMC4(); BARR();
        k0 += 128;
    }
    asm volatile("s_waitcnt vmcnt(0)" ::: "memory");

    // ---- epilogue: m = m0 + wm*128 + mf*16 + quad*4 + rr,
    //                n = n0 + wn*64 + nf*16 + l15
    const int nf_frames = nfp[0];
    float bb[4];
#pragma unroll
    for (int nf = 0; nf < 4; ++nf) bb[nf] = bias[n0 + wn * 64 + nf * 16 + l15];
#pragma unroll
    for (int mf = 0; mf < 8; ++mf)
#pragma unroll
        for (int nf = 0; nf < 4; ++nf)
#pragma unroll
            for (int rr = 0; rr < 4; ++rr) acc[mf][nf][rr] += bb[nf];

    if constexpr (EPI == 0) {  // Q-proj: RoPE + scale -> q_h[b][h][lq][hd]
        // scale = 0.125 * log2(e): softmax then uses exp2 directly
        const float SCALE = 0.18033688011112042f;
        const float l2b = 13.287712379549449f;
        const float inv0 = exp2f(-((float)l15 * (1.0f / 32.0f)) * l2b);
        const float inv1 = exp2f(-((float)(16 + l15) * (1.0f / 32.0f)) * l2b);
        _Float16* O = (_Float16*)Cp;
        const int head = (n0 + wn * 64) >> 6;
        int dv = 4096;
        bool uni = false;
        float us0 = 0.f, uc0 = 1.f, us1 = 0.f, uc1 = 1.f;
        if (nf_frames > 1) {
            dv = 4096 / nf_frames;
            const int lqb = (m0 + wm * 128) & 4095;
            uni = (lqb / dv) == ((lqb + 127) / dv);
            if (uni) {
                const float fp = (float)(lqb / dv);
                __sincosf(fp * inv0, &us0, &uc0);
                __sincosf(fp * inv1, &us1, &uc1);
            }
        }
#pragma unroll
        for (int mf = 0; mf < 8; ++mf) {
#pragma unroll
            for (int rr = 0; rr < 4; ++rr) {
                const int m = m0 + wm * 128 + mf * 16 + quad * 4 + rr;
                const int b = m >> 12, lq = m & 4095;
                if (nf_frames > 1) {
                    float s0, c0, s1, c1;
                    if (uni) {
                        s0 = us0; c0 = uc0; s1 = us1; c1 = uc1;
                    } else {
                        const int pos = lq / dv;
                        __sincosf((float)pos * inv0, &s0, &c0);
                        __sincosf((float)pos * inv1, &s1, &c1);
                    }
                    const float x0 = acc[mf][0][rr], x2 = acc[mf][2][rr];
                    const float x1 = acc[mf][1][rr], x3 = acc[mf][3][rr];
                    acc[mf][0][rr] = x0 * c0 - x2 * s0;
                    acc[mf][2][rr] = x2 * c0 + x0 * s0;
                    acc[mf][1][rr] = x1 * c1 - x3 * s1;
                    acc[mf][3][rr] = x3 * c1 + x1 * s1;
                }
                const size_t base = (((size_t)(b * 16 + head)) * 4096 + lq) * 64;
#pragma unroll
                for (int nf = 0; nf < 4; ++nf)
                    O[base + nf * 16 + l15] = (_Float16)(acc[mf][nf][rr] * SCALE);
            }
        }
    } else {  // O-proj fp32 row-major
        float* O = (float*)Cp;
#pragma unroll
        for (int mf = 0; mf < 8; ++mf) {
#pragma unroll
            for (int rr = 0; rr < 4; ++rr) {
                const int m = m0 + wm * 128 + mf * 16 + quad * 4 + rr;
#pragma unroll
                for (int nf = 0; nf < 4; ++nf)
                    O[(size_t)m * 1024 + n0 + wn * 64 + nf * 16 + l15] =
                        acc[mf][nf][rr];
            }
        }
    }
#undef STAGE
#undef LDA4
#undef LDB2
#undef QUAD
#undef FENCE
#undef BARR
#undef LGKM0
#undef VMC4
}

// ---------------------------------------------------------------------------
// Attention v7.  Structure of v6 (8 waves, K+V in LDS swizzled, Q prefetch,
// chunk rotation) + VALU diet:
//   - scores arrive pre-scaled by log2e/8 -> exp2f (no mul inside exp)
//   - row-sum via ones-A MFMA over the P fragments (kills 64 v_add + 2
//     shuffles per chunk; MFMA K-reduction gives every lane its full sum)
//   - P->fp16 via v_cvt_pkrtz pairs (64 -> 32 cvt insts)
//   - max3-friendly fmax tree
// ---------------------------------------------------------------------------
__global__ __launch_bounds__(512, 4) void attn5(const _Float16* __restrict__ qh,
                                                const _Float16* __restrict__ kh,
                                                const _Float16* __restrict__ vp,
                                                _Float16* __restrict__ attn) {
    __shared__ _Float16 Ks[256 * 64];  // swizzled: chunk c of row r at c^(r&7)
    __shared__ _Float16 Vs[64 * 256];  // swizzled: chunk s of row hd at s^((hd&7)<<2)

    const int tid = threadIdx.x;
    const int w = tid >> 6, lane = tid & 63, quad = lane >> 4, l15 = lane & 15;
    const int bh = blockIdx.x, b = bh >> 4, h = bh & 15, kvh = h >> 2;
    const int q0 = blockIdx.y * 512;

    const _Float16* kb = kh + (size_t)(b * 4 + kvh) * 256 * 64;
    const _Float16* vb = vp + (size_t)(b * 4 + kvh) * 64 * 256;
    const _Float16* qb = qh + ((size_t)bh * 4096 + q0) * 64;

    // ---- stage K into LDS (2048 x 16B chunks, 4/thread), source-swizzled
#pragma unroll
    for (int i = 0; i < 4; ++i) {
        const int id = i * 512 + tid;
        const int r = id >> 3;
        const int c = (id & 7) ^ (r & 7);
        async_cp16(kb + (size_t)r * 64 + c * 8, Ks + i * 4096 + w * 512);
    }
    // ---- stage V_pi into LDS (2048 x 16B chunks), source-swizzled
#pragma unroll
    for (int i = 0; i < 4; ++i) {
        const int id = i * 512 + tid;
        const int hd = id >> 5;
        const int s5 = id & 31;
        const int c = s5 ^ ((hd & 7) << 2);
        async_cp16(vb + (size_t)hd * 256 + c * 8, Vs + i * 4096 + w * 512);
    }
    __syncthreads();

    const int sw = l15 & 7;        // K read-side swizzle key (row&7 == l15&7)
    const int p0 = quad ^ sw;      // slot of k-chunk quad (hd 0..31)
    const int vsw = sw << 2;       // V read-side swizzle key (hd&7 == l15&7)
    const int crot = w & 3;        // per-wave chunk rotation (de-convoy)

    f16x8 ones;
#pragma unroll
    for (int j = 0; j < 8; ++j) ones[j] = (_Float16)1.0f;

    // prefetch Q for first chunk
    const _Float16* qpre = qb + (size_t)(w * 64 + crot * 16 + l15) * 64 + quad * 8;
    f16x8 bq0 = *(const f16x8*)qpre;
    f16x8 bq1 = *(const f16x8*)(qpre + 32);

#pragma unroll 1
    for (int cc = 0; cc < 4; ++cc) {
        const int chunk = (cc + crot) & 3;
        const int qrow = w * 64 + chunk * 16;

        // issue next chunk's Q loads now; consumed next iteration
        const int nchunk = (cc + 1 + crot) & 3;
        const _Float16* np = qb + (size_t)(w * 64 + nchunk * 16 + l15) * 64 + quad * 8;
        const f16x8 nq0 = *(const f16x8*)np;
        const f16x8 nq1 = *(const f16x8*)(np + 32);

        // S^T = K @ Q^T : lane holds S[q=l15][kv = t*16 + quad*4 + rr]
        f32x4 st[16];
#pragma unroll
        for (int t = 0; t < 16; ++t)
#pragma unroll
            for (int rr = 0; rr < 4; ++rr) st[t][rr] = 0.f;

#pragma unroll
        for (int t = 0; t < 16; ++t) {
            const int row = t * 16 + l15;
            const f16x8 ka0 = *(const f16x8*)&Ks[row * 64 + p0 * 8];
            const f16x8 ka1 = *(const f16x8*)&Ks[row * 64 + (p0 ^ 4) * 8];
            st[t] = MFMA16(ka0, bq0, st[t]);
            st[t] = MFMA16(ka1, bq1, st[t]);
        }

        // row max (q = l15): fmax tree, then 2 shuffles
        float tm[16];
#pragma unroll
        for (int t = 0; t < 16; ++t)
            tm[t] = fmaxf(fmaxf(fmaxf(st[t][0], st[t][1]), st[t][2]), st[t][3]);
        const float a0 = fmaxf(fmaxf(tm[0], tm[1]), tm[2]);
        const float a1 = fmaxf(fmaxf(tm[3], tm[4]), tm[5]);
        const float a2 = fmaxf(fmaxf(tm[6], tm[7]), tm[8]);
        const float a3 = fmaxf(fmaxf(tm[9], tm[10]), tm[11]);
        const float a4 = fmaxf(fmaxf(tm[12], tm[13]), tm[14]);
        float rm = fmaxf(fmaxf(fmaxf(a0, a1), a2), fmaxf(fmaxf(a3, a4), tm[15]));
        rm = fmaxf(rm, __shfl_xor(rm, 16, 64));
        rm = fmaxf(rm, __shfl_xor(rm, 32, 64));

        // P = exp2(S - rm)  (scores pre-scaled by log2e/8 at Q-proj)
#pragma unroll
        for (int t = 0; t < 16; ++t)
#pragma unroll
            for (int rr = 0; rr < 4; ++rr)
                st[t][rr] = exp2f(st[t][rr] - rm);

        // opaque 0 offset: keep the 32 V ds_reads inside this iteration
        int vo = 0;
        asm volatile("" : "+v"(vo));

        // O^T = V_pi @ P^T : 4 hd-tiles + ones-tile (row sum), k = 256
        f32x4 o[4];
#pragma unroll
        for (int nt = 0; nt < 4; ++nt)
#pragma unroll
            for (int rr = 0; rr < 4; ++rr) o[nt][rr] = 0.f;
        f32x4 osum;
#pragma unroll
        for (int rr = 0; rr < 4; ++rr) osum[rr] = 0.f;

#pragma unroll
        for (int c = 0; c < 8; ++c) {
            // P^T B-frag: slot (quad, j) <-> kv = 32c + 16*(j>>2) + 4*quad + (j&3)
            union { fp16x2 h2[4]; f16x8 v; } pbu;
            pbu.h2[0] = __builtin_amdgcn_cvt_pkrtz(st[2 * c][0], st[2 * c][1]);
            pbu.h2[1] = __builtin_amdgcn_cvt_pkrtz(st[2 * c][2], st[2 * c][3]);
            pbu.h2[2] = __builtin_amdgcn_cvt_pkrtz(st[2 * c + 1][0], st[2 * c + 1][1]);
            pbu.h2[3] = __builtin_amdgcn_cvt_pkrtz(st[2 * c + 1][2], st[2 * c + 1][3]);
            const f16x8 pb = pbu.v;
            osum = MFMA16(ones, pb, osum);
#pragma unroll
            for (int nt = 0; nt < 4; ++nt) {
                const f16x8 va = *(const f16x8*)&Vs[(nt * 16 + l15) * 256 +
                                                   (((c * 4 + quad) ^ vsw) * 8) + vo];
                o[nt] = MFMA16(va, pb, o[nt]);
            }
        }

        // all rows of the ones-tile C equal the full row sum for q = l15
        const float ir = 1.0f / osum[0];

        // store: O^T C-frag: q = l15, hd = nt*16 + quad*4 + rr -> f16x4 packs
        const size_t rowbase = ((size_t)b * 4096 + q0 + qrow + l15) * 1024 + h * 64;
#pragma unroll
        for (int nt = 0; nt < 4; ++nt) {
            f16x4 ov;
#pragma unroll
            for (int rr = 0; rr < 4; ++rr) ov[rr] = (_Float16)(o[nt][rr] * ir);
            *(f16x4*)&attn[rowbase + nt * 16 + quad * 4] = ov;
        }

        bq0 = nq0; bq1 = nq1;
    }
}

// ---------------------------------------------------------------------------
extern "C" void kernel_launch(void* const* d_in, const int* in_sizes, int n_in,
                              void* d_out, int out_size, void* d_ws, size_t ws_size,
                              hipStream_t stream) {
    const float* patches = (const float*)d_in[0];
    const float* latents = (const float*)d_in[1];
    const float* Wq = (const float*)d_in[2];
    const float* bq = (const float*)d_in[3];
    const float* Wk = (const float*)d_in[4];
    const float* bk = (const float*)d_in[5];
    const float* Wv = (const float*)d_in[6];
    const float* bv = (const float*)d_in[7];
    const float* Wo = (const float*)d_in[8];
    const float* bo = (const float*)d_in[9];
    const int*   nf = (const int*)d_in[10];
    float* out = (float*)d_out;
    (void)in_sizes; (void)n_in; (void)out_size; (void)ws_size;

    char* p = (char*)d_ws;
    _Float16* WqT  = (_Float16*)p; p += (size_t)1024 * 1024 * 2;
    _Float16* WkvT = (_Float16*)p; p += (size_t)512 * 1024 * 2;
    _Float16* WoT  = (_Float16*)p; p += (size_t)1024 * 1024 * 2;
    float*    bkv  = (float*)p;    p += 4096;
    _Float16* p16  = (_Float16*)p; p += (size_t)4 * 4096 * 1024 * 2;
    _Float16* l16  = (_Float16*)p; p += (size_t)4 * 256 * 1024 * 2;
    _Float16* q_h  = (_Float16*)p; p += (size_t)4 * 16 * 4096 * 64 * 2;
    _Float16* k_h  = (_Float16*)p; p += (size_t)4 * 4 * 256 * 64 * 2;
    _Float16* v_pi = (_Float16*)p; p += (size_t)4 * 4 * 256 * 64 * 2;  // after k_h
    _Float16* attn_h = (_Float16*)p; p += (size_t)16384 * 1024 * 2;

    prep<<<18433, 256, 0, stream>>>((const float4*)patches, (const float4*)latents,
                                    (f16x4*)p16, (f16x4*)l16,
                                    Wq, Wk, Wv, Wo, WqT, WkvT, WoT, bk, bv, bkv);

    gemm32<1><<<dim3(4, 4), 256, 0, stream>>>(l16, WkvT, bkv, k_h, nf);
    gemm8p<0><<<256, 512, 0, stream>>>(p16, WqT, bq, q_h, nf);

    attn5<<<dim3(64, 8), 512, 0, stream>>>(q_h, k_h, v_pi, attn_h);

    gemm8p<2><<<256, 512, 0, stream>>>(attn_h, WoT, bo, out, nf);
}

// Round 7
// 281.581 us; speedup vs baseline: 1.0980x; 1.0086x over previous
//
#include <hip/hip_runtime.h>
#include <hip/hip_fp16.h>
#include <cstdint>

typedef _Float16 f16x8 __attribute__((ext_vector_type(8)));
typedef _Float16 f16x4 __attribute__((ext_vector_type(4)));
typedef __fp16   fp16x2 __attribute__((ext_vector_type(2)));  // cvt_pkrtz return type
typedef float    f32x4 __attribute__((ext_vector_type(4)));
typedef float    f32x16 __attribute__((ext_vector_type(16)));

#define MFMA16(a, b, c) __builtin_amdgcn_mfma_f32_16x16x32_f16((a), (b), (c), 0, 0, 0)
#define MFMA32(a, b, c) __builtin_amdgcn_mfma_f32_32x32x16_f16((a), (b), (c), 0, 0, 0)

// B=4, LQ=4096, LKV=256, D=1024, H=16, KVH=4, HD=64

__device__ __forceinline__ void async_cp16(const _Float16* g, _Float16* l) {
    __builtin_amdgcn_global_load_lds(
        (const __attribute__((address_space(1))) void*)g,
        (__attribute__((address_space(3))) void*)l, 16, 0, 0);
}

// ---------------------------------------------------------------------------
// prep: ONE launch fusing (a) fp32->fp16 convert of patches+latents,
// (b) all 4 weight transposes, (c) bkv concat.  No mutual deps; flat grid.
// ---------------------------------------------------------------------------
__global__ __launch_bounds__(256) void prep(
    const float4* __restrict__ patches, const float4* __restrict__ latents,
    f16x4* __restrict__ p16, f16x4* __restrict__ l16,
    const float* __restrict__ Wq, const float* __restrict__ Wk,
    const float* __restrict__ Wv, const float* __restrict__ Wo,
    _Float16* __restrict__ WqT, _Float16* __restrict__ WkvT,
    _Float16* __restrict__ WoT,
    const float* __restrict__ bk, const float* __restrict__ bv,
    float* __restrict__ bkv) {
    __shared__ float T[64][65];
    const int tid = threadIdx.x;
    const int bid = blockIdx.x;

    if (bid < 17408) {  // cvt
        const long i = (long)bid * 256 + tid;
        const float4 v = (i < 4194304) ? patches[i] : latents[i - 4194304];
        f16x4 o;
        o[0] = (_Float16)v.x; o[1] = (_Float16)v.y;
        o[2] = (_Float16)v.z; o[3] = (_Float16)v.w;
        if (i < 4194304) p16[i] = o; else l16[i - 4194304] = o;
        return;
    }
    if (bid == 18432) {  // catbias
        bkv[tid] = bk[tid];
        bkv[256 + tid] = bv[tid];
        return;
    }
    // transpose: fp32 [K][N] -> fp16 [N][K]
    const int t = bid - 17408;
    const int z = t >> 8, rem = t & 255, xb = rem & 15, yb = rem >> 4;
    const float* W;
    _Float16* WT;
    int Nd;
    if (z == 0)      { W = Wq; WT = WqT;                       Nd = 1024; }
    else if (z == 1) { W = Wk; WT = WkvT;                      Nd = 256;  }
    else if (z == 2) { W = Wv; WT = WkvT + (size_t)256 * 1024; Nd = 256;  }
    else             { W = Wo; WT = WoT;                       Nd = 1024; }
    const int n0 = xb * 64, k0 = yb * 64;
    if (n0 >= Nd) return;

    const int nl = tid & 63, kg = tid >> 6;
#pragma unroll
    for (int i = 0; i < 16; ++i) {
        const int kl = kg * 16 + i;
        T[kl][nl] = W[(size_t)(k0 + kl) * Nd + n0 + nl];
    }
    __syncthreads();
    const int kl = tid & 63;
#pragma unroll
    for (int i = 0; i < 16; ++i) {
        const int nl2 = kg * 16 + i;
        WT[(size_t)(n0 + nl2) * 1024 + k0 + kl] = (_Float16)T[kl][nl2];
    }
}

// ---------------------------------------------------------------------------
// Small-M GEMM (KV-proj only): 2-barrier structure, 256x128 tile.
// ---------------------------------------------------------------------------
template <int EPI>
__global__ __launch_bounds__(256, 2) void gemm32(const _Float16* __restrict__ A,
                                                 const _Float16* __restrict__ BT,
                                                 const float* __restrict__ bias,
                                                 void* __restrict__ Cp,
                                                 const int* __restrict__ nfp) {
    constexpr int K = 1024;
    __shared__ _Float16 As[256 * 64];
    __shared__ _Float16 Bs[128 * 64];

    const int tid = threadIdx.x;
    const int lane = tid & 63, l31 = lane & 31, hh = lane >> 5;
    const int w = tid >> 6, wm = w >> 1, wn = w & 1;

    const int n0 = blockIdx.x * 128;
    const int m0 = blockIdx.y * 256;

    f32x16 acc[4][2];
#pragma unroll
    for (int mt = 0; mt < 4; ++mt)
#pragma unroll
        for (int nt = 0; nt < 2; ++nt)
#pragma unroll
            for (int v = 0; v < 16; ++v) acc[mt][nt][v] = 0.f;

    for (int k0 = 0; k0 < K; k0 += 64) {
#pragma unroll
        for (int i = 0; i < 8; ++i) {
            const int id = i * 256 + tid;
            const int r = id >> 3;
            const int c = (id & 7) ^ (r & 7);
            async_cp16(A + (size_t)(m0 + r) * K + k0 + c * 8,
                       As + i * 2048 + w * 512);
        }
#pragma unroll
        for (int i = 0; i < 4; ++i) {
            const int id = i * 256 + tid;
            const int r = id >> 3;
            const int c = (id & 7) ^ (r & 7);
            async_cp16(BT + (size_t)(n0 + r) * K + k0 + c * 8,
                       Bs + i * 2048 + w * 512);
        }
        __syncthreads();

#pragma unroll
        for (int kk = 0; kk < 4; ++kk) {
            f16x8 af[4], bf[2];
#pragma unroll
            for (int mt = 0; mt < 4; ++mt) {
                const int row = wm * 128 + mt * 32 + l31;
                const int pc = (kk * 2 + hh) ^ (row & 7);
                af[mt] = *(const f16x8*)&As[row * 64 + pc * 8];
            }
#pragma unroll
            for (int nt = 0; nt < 2; ++nt) {
                const int row = wn * 64 + nt * 32 + l31;
                const int pc = (kk * 2 + hh) ^ (row & 7);
                bf[nt] = *(const f16x8*)&Bs[row * 64 + pc * 8];
            }
#pragma unroll
            for (int mt = 0; mt < 4; ++mt)
#pragma unroll
                for (int nt = 0; nt < 2; ++nt)
                    acc[mt][nt] = MFMA32(af[mt], bf[nt], acc[mt][nt]);
        }
        __syncthreads();
    }

    const int nf = nfp[0];
    const int nbase = n0 + wn * 64;

    float bb[2];
#pragma unroll
    for (int nt = 0; nt < 2; ++nt) bb[nt] = bias[nbase + nt * 32 + l31];
#pragma unroll
    for (int mt = 0; mt < 4; ++mt)
#pragma unroll
        for (int nt = 0; nt < 2; ++nt)
#pragma unroll
            for (int v = 0; v < 16; ++v) acc[mt][nt][v] += bb[nt];

    {  // K/V fused (N=512)
        _Float16* kout = (_Float16*)Cp;
        _Float16* vout = kout + (size_t)4 * 4 * 256 * 64;
        if (nbase < 256) {
            const float l2b = 13.287712379549449f;
            const float inv = exp2f(-((float)l31 * (1.0f / 32.0f)) * l2b);
            const int dv = 256 / (nf > 1 ? nf : 1);
            const int kvh = nbase >> 6;
#pragma unroll
            for (int mt = 0; mt < 4; ++mt) {
#pragma unroll
                for (int v = 0; v < 16; ++v) {
                    const int m = m0 + wm * 128 + mt * 32 + (v & 3) + 8 * (v >> 2) + 4 * hh;
                    const int b = m >> 8, lkv = m & 255;
                    if (nf > 1) {
                        const int pos = lkv / dv;
                        float s, c;
                        __sincosf((float)pos * inv, &s, &c);
                        const float x1 = acc[mt][0][v], x2 = acc[mt][1][v];
                        acc[mt][0][v] = x1 * c - x2 * s;
                        acc[mt][1][v] = x2 * c + x1 * s;
                    }
#pragma unroll
                    for (int nt = 0; nt < 2; ++nt) {
                        const int hd = nt * 32 + l31;
                        kout[(((size_t)(b * 4 + kvh)) * 256 + lkv) * 64 + hd] =
                            (_Float16)acc[mt][nt][v];
                    }
                }
            }
        } else {
            const int kvh = (nbase - 256) >> 6;
#pragma unroll
            for (int mt = 0; mt < 4; ++mt) {
#pragma unroll
                for (int v = 0; v < 16; ++v) {
                    const int m = m0 + wm * 128 + mt * 32 + (v & 3) + 8 * (v >> 2) + 4 * hh;
                    const int b = m >> 8, lkv = m & 255;
                    // pi-permuted kv slot: swap the 16s bit below the 4s bits
                    const int s = (lkv & 0xE0) | ((lkv & 12) << 1) |
                                  ((lkv & 16) >> 2) | (lkv & 3);
#pragma unroll
                    for (int nt = 0; nt < 2; ++nt) {
                        const int hd = nt * 32 + l31;
                        vout[(((size_t)(b * 4 + kvh)) * 64 + hd) * 256 + s] =
                            (_Float16)acc[mt][nt][v];
                    }
                }
            }
        }
    }
}

// ---------------------------------------------------------------------------
// 8-phase 256x256 GEMM (T2+T3+T4+T5).  EPI 0: Q-proj (bias+RoPE, scale folds
// log2e/8 so attn can use exp2 directly).  EPI 2: O-proj (fp32).
// ---------------------------------------------------------------------------
template <int EPI>
__global__ __launch_bounds__(512, 2) void gemm8p(const _Float16* __restrict__ A,
                                                 const _Float16* __restrict__ BT,
                                                 const float* __restrict__ bias,
                                                 void* __restrict__ Cp,
                                                 const int* __restrict__ nfp) {
    constexpr int K = 1024;
    __shared__ alignas(16) _Float16 lds[2][2][2][128 * 64];  // [buf][A=0/B=1][half]

    const int tid = threadIdx.x;
    const int lane = tid & 63, quad = lane >> 4, l15 = lane & 15;
    const int w = tid >> 6, wm = w >> 2, wn = w & 3;

    // bijective XCD swizzle: 256 blocks, 8 XCDs -> 32-block m-stripes
    int lin = blockIdx.x;
    lin = (lin & 7) * 32 + (lin >> 3);
    const int m0 = (lin >> 2) * 256;
    const int n0 = (lin & 3) * 256;

    f32x4 acc[8][4];
#pragma unroll
    for (int mf = 0; mf < 8; ++mf)
#pragma unroll
        for (int nf = 0; nf < 4; ++nf)
#pragma unroll
            for (int rr = 0; rr < 4; ++rr) acc[mf][nf][rr] = 0.f;

    f16x8 ra[4][2], rb[4][2];

#define STAGE(BUF, MAT, HALF, KK0)                                              \
    {                                                                           \
        const _Float16* g_ = (MAT) ? BT : A;                                    \
        const int rb_ = ((MAT) ? n0 : m0) + (HALF) * 128;                       \
        _Float16* dst_ = &lds[BUF][MAT][HALF][0];                               \
        _Pragma("unroll") for (int i_ = 0; i_ < 2; ++i_) {                      \
            const int id_ = i_ * 512 + tid;                                     \
            const int r_ = id_ >> 3;                                            \
            const int c_ = (id_ & 7) ^ (r_ & 7);                                \
            async_cp16(g_ + (size_t)(rb_ + r_) * K + (KK0) + c_ * 8,            \
                       dst_ + i_ * 4096 + w * 512);                             \
        }                                                                       \
    }

#define LDA4(BUF, MH)                                                           \
    _Pragma("unroll") for (int i_ = 0; i_ < 4; ++i_)                            \
    _Pragma("unroll") for (int ks_ = 0; ks_ < 2; ++ks_) {                       \
        const int row_ = ((MH) * 4 + i_) * 16 + l15;                            \
        ra[i_][ks_] = *(const f16x8*)&lds[BUF][0][wm]                           \
            [row_ * 64 + (((ks_ * 4 + quad) ^ (l15 & 7)) * 8)];                 \
    }

#define LDB2(BUF, NFROM)                                                        \
    _Pragma("unroll") for (int j_ = 0; j_ < 2; ++j_)                            \
    _Pragma("unroll") for (int ks_ = 0; ks_ < 2; ++ks_) {                       \
        const int nf_ = (NFROM) + j_;                                           \
        const int row_ = (wn & 1) * 64 + nf_ * 16 + l15;                        \
        rb[nf_][ks_] = *(const f16x8*)&lds[BUF][1][wn >> 1]                     \
            [row_ * 64 + (((ks_ * 4 + quad) ^ (l15 & 7)) * 8)];                 \
    }

#define QUAD(QM, QN)                                                            \
    {                                                                           \
        __builtin_amdgcn_s_setprio(1);                                          \
        _Pragma("unroll") for (int i_ = 0; i_ < 4; ++i_)                        \
        _Pragma("unroll") for (int j_ = 0; j_ < 2; ++j_)                        \
        _Pragma("unroll") for (int ks_ = 0; ks_ < 2; ++ks_)                     \
            acc[(QM) * 4 + i_][(QN) * 2 + j_] =                                 \
                MFMA16(ra[i_][ks_], rb[(QN) * 2 + j_][ks_],                     \
                       acc[(QM) * 4 + i_][(QN) * 2 + j_]);                      \
        __builtin_amdgcn_s_setprio(0);                                          \
    }

#define FENCE() asm volatile("" ::: "memory")
#define BARR()  FENCE(); __builtin_amdgcn_s_barrier(); FENCE()
#define LGKM0() asm volatile("s_waitcnt lgkmcnt(0)" ::: "memory");              \
                __builtin_amdgcn_sched_barrier(0)
#define VMC4()  asm volatile("s_waitcnt vmcnt(4)" ::: "memory")

    // prologue: tile0 (all 4 halves) + tile1 (B0, A0)
    STAGE(0, 1, 0, 0);
    STAGE(0, 1, 1, 0);
    STAGE(0, 0, 0, 0);
    STAGE(0, 0, 1, 0);
    STAGE(1, 1, 0, 64);
    STAGE(1, 0, 0, 64);
    VMC4();
    BARR();

    int k0 = 0;
#pragma unroll 1
    for (int it = 0; it < 8; ++it) {
        const int k_t1 = k0 + 64;
        const int k_n0 = (k0 + 128 < K) ? k0 + 128 : K - 64;  // tile t0+2
        const int k_n1 = (k0 + 192 < K) ? k0 + 192 : K - 64;  // tile t1+2
        // P0
        LDA4(0, 0); LDB2(0, 0);
        STAGE(1, 1, 1, k_t1);
        BARR(); LGKM0(); QUAD(0, 0); BARR();
        // P1
        LDB2(0, 2);
        STAGE(1, 0, 1, k_t1);
        BARR(); LGKM0(); QUAD(0, 1); BARR();
        // P2
        LDA4(0, 1);
        STAGE(0, 1, 0, k_n0);
        BARR(); LGKM0(); QUAD(1, 0); BARR();
        // P3
        STAGE(0, 1, 1, k_n0);
        BARR(); LGKM0(); QUAD(1, 1); VMC4(); BARR();
        // P4
        LDA4(1, 0); LDB2(1, 0);
        STAGE(0, 0, 0, k_n0);
        BARR(); LGKM0(); QUAD(0, 0); BARR();
        // P5
        LDB2(1, 2);
        STAGE(0, 0, 1, k_n0);
        BARR(); LGKM0(); QUAD(0, 1); BARR();
        // P6
        LDA4(1, 1);
        STAGE(1, 1, 0, k_n1);
        BARR(); LGKM0(); QUAD(1, 0); BARR();
        // P7
        STAGE(1, 0, 0, k_n1);
        BARR(); LGKM0(); QUAD(1, 1); VMC4(); BARR();
        k0 += 128;
    }
    asm volatile("s_waitcnt vmcnt(0)" ::: "memory");

    // ---- epilogue: m = m0 + wm*128 + mf*16 + quad*4 + rr,
    //                n = n0 + wn*64 + nf*16 + l15
    const int nf_frames = nfp[0];
    float bb[4];
#pragma unroll
    for (int nf = 0; nf < 4; ++nf) bb[nf] = bias[n0 + wn * 64 + nf * 16 + l15];
#pragma unroll
    for (int mf = 0; mf < 8; ++mf)
#pragma unroll
        for (int nf = 0; nf < 4; ++nf)
#pragma unroll
            for (int rr = 0; rr < 4; ++rr) acc[mf][nf][rr] += bb[nf];

    if constexpr (EPI == 0) {  // Q-proj: RoPE + scale -> q_h[b][h][lq][hd]
        // scale = 0.125 * log2(e): softmax then uses exp2 directly
        const float SCALE = 0.18033688011112042f;
        const float l2b = 13.287712379549449f;
        const float inv0 = exp2f(-((float)l15 * (1.0f / 32.0f)) * l2b);
        const float inv1 = exp2f(-((float)(16 + l15) * (1.0f / 32.0f)) * l2b);
        _Float16* O = (_Float16*)Cp;
        const int head = (n0 + wn * 64) >> 6;
        int dv = 4096;
        bool uni = false;
        float us0 = 0.f, uc0 = 1.f, us1 = 0.f, uc1 = 1.f;
        if (nf_frames > 1) {
            dv = 4096 / nf_frames;
            const int lqb = (m0 + wm * 128) & 4095;
            uni = (lqb / dv) == ((lqb + 127) / dv);
            if (uni) {
                const float fp = (float)(lqb / dv);
                __sincosf(fp * inv0, &us0, &uc0);
                __sincosf(fp * inv1, &us1, &uc1);
            }
        }
#pragma unroll
        for (int mf = 0; mf < 8; ++mf) {
#pragma unroll
            for (int rr = 0; rr < 4; ++rr) {
                const int m = m0 + wm * 128 + mf * 16 + quad * 4 + rr;
                const int b = m >> 12, lq = m & 4095;
                if (nf_frames > 1) {
                    float s0, c0, s1, c1;
                    if (uni) {
                        s0 = us0; c0 = uc0; s1 = us1; c1 = uc1;
                    } else {
                        const int pos = lq / dv;
                        __sincosf((float)pos * inv0, &s0, &c0);
                        __sincosf((float)pos * inv1, &s1, &c1);
                    }
                    const float x0 = acc[mf][0][rr], x2 = acc[mf][2][rr];
                    const float x1 = acc[mf][1][rr], x3 = acc[mf][3][rr];
                    acc[mf][0][rr] = x0 * c0 - x2 * s0;
                    acc[mf][2][rr] = x2 * c0 + x0 * s0;
                    acc[mf][1][rr] = x1 * c1 - x3 * s1;
                    acc[mf][3][rr] = x3 * c1 + x1 * s1;
                }
                const size_t base = (((size_t)(b * 16 + head)) * 4096 + lq) * 64;
#pragma unroll
                for (int nf = 0; nf < 4; ++nf)
                    O[base + nf * 16 + l15] = (_Float16)(acc[mf][nf][rr] * SCALE);
            }
        }
    } else {  // O-proj fp32 row-major
        float* O = (float*)Cp;
#pragma unroll
        for (int mf = 0; mf < 8; ++mf) {
#pragma unroll
            for (int rr = 0; rr < 4; ++rr) {
                const int m = m0 + wm * 128 + mf * 16 + quad * 4 + rr;
#pragma unroll
                for (int nf = 0; nf < 4; ++nf)
                    O[(size_t)m * 1024 + n0 + wn * 64 + nf * 16 + l15] =
                        acc[mf][nf][rr];
            }
        }
    }
#undef STAGE
#undef LDA4
#undef LDB2
#undef QUAD
#undef FENCE
#undef BARR
#undef LGKM0
#undef VMC4
}

// ---------------------------------------------------------------------------
// Attention v9 = v7 structure with __launch_bounds__(512, 2).
// Theory: at (512,4) the 128-reg cap forced st[16] (64 f32 QK accumulators)
// into AGPRs (VGPR_Count=64), so every softmax touch paid v_accvgpr_read/
// write -- ~512 cyc/chunk of move traffic, the bulk of VALUBusy 46.7%.
// At (512,2) the 256-reg budget lets the compiler keep st in arch VGPRs
// (builtin MFMA handles all hazards -- round 6's asm attempt violated them).
// Trade: 1 block/CU instead of 2 (2 waves/SIMD), acceptable since the kernel
// is VALU-throughput-bound, not latency-bound.
// ---------------------------------------------------------------------------
__global__ __launch_bounds__(512, 2) void attn5(const _Float16* __restrict__ qh,
                                                const _Float16* __restrict__ kh,
                                                const _Float16* __restrict__ vp,
                                                _Float16* __restrict__ attn) {
    __shared__ _Float16 Ks[256 * 64];  // swizzled: chunk c of row r at c^(r&7)
    __shared__ _Float16 Vs[64 * 256];  // swizzled: chunk s of row hd at s^((hd&7)<<2)

    const int tid = threadIdx.x;
    const int w = tid >> 6, lane = tid & 63, quad = lane >> 4, l15 = lane & 15;
    const int bh = blockIdx.x, b = bh >> 4, h = bh & 15, kvh = h >> 2;
    const int q0 = blockIdx.y * 512;

    const _Float16* kb = kh + (size_t)(b * 4 + kvh) * 256 * 64;
    const _Float16* vb = vp + (size_t)(b * 4 + kvh) * 64 * 256;
    const _Float16* qb = qh + ((size_t)bh * 4096 + q0) * 64;

    // ---- stage K into LDS (2048 x 16B chunks, 4/thread), source-swizzled
#pragma unroll
    for (int i = 0; i < 4; ++i) {
        const int id = i * 512 + tid;
        const int r = id >> 3;
        const int c = (id & 7) ^ (r & 7);
        async_cp16(kb + (size_t)r * 64 + c * 8, Ks + i * 4096 + w * 512);
    }
    // ---- stage V_pi into LDS (2048 x 16B chunks), source-swizzled
#pragma unroll
    for (int i = 0; i < 4; ++i) {
        const int id = i * 512 + tid;
        const int hd = id >> 5;
        const int s5 = id & 31;
        const int c = s5 ^ ((hd & 7) << 2);
        async_cp16(vb + (size_t)hd * 256 + c * 8, Vs + i * 4096 + w * 512);
    }
    __syncthreads();

    const int sw = l15 & 7;        // K read-side swizzle key (row&7 == l15&7)
    const int p0 = quad ^ sw;      // slot of k-chunk quad (hd 0..31)
    const int vsw = sw << 2;       // V read-side swizzle key (hd&7 == l15&7)
    const int crot = w & 3;        // per-wave chunk rotation (de-convoy)

    f16x8 ones;
#pragma unroll
    for (int j = 0; j < 8; ++j) ones[j] = (_Float16)1.0f;

    // prefetch Q for first chunk
    const _Float16* qpre = qb + (size_t)(w * 64 + crot * 16 + l15) * 64 + quad * 8;
    f16x8 bq0 = *(const f16x8*)qpre;
    f16x8 bq1 = *(const f16x8*)(qpre + 32);

#pragma unroll 1
    for (int cc = 0; cc < 4; ++cc) {
        const int chunk = (cc + crot) & 3;
        const int qrow = w * 64 + chunk * 16;

        // issue next chunk's Q loads now; consumed next iteration
        const int nchunk = (cc + 1 + crot) & 3;
        const _Float16* np = qb + (size_t)(w * 64 + nchunk * 16 + l15) * 64 + quad * 8;
        const f16x8 nq0 = *(const f16x8*)np;
        const f16x8 nq1 = *(const f16x8*)(np + 32);

        // S^T = K @ Q^T : lane holds S[q=l15][kv = t*16 + quad*4 + rr]
        f32x4 st[16];
#pragma unroll
        for (int t = 0; t < 16; ++t)
#pragma unroll
            for (int rr = 0; rr < 4; ++rr) st[t][rr] = 0.f;

#pragma unroll
        for (int t = 0; t < 16; ++t) {
            const int row = t * 16 + l15;
            const f16x8 ka0 = *(const f16x8*)&Ks[row * 64 + p0 * 8];
            const f16x8 ka1 = *(const f16x8*)&Ks[row * 64 + (p0 ^ 4) * 8];
            st[t] = MFMA16(ka0, bq0, st[t]);
            st[t] = MFMA16(ka1, bq1, st[t]);
        }

        // row max (q = l15): fmax tree, then 2 shuffles
        float tm[16];
#pragma unroll
        for (int t = 0; t < 16; ++t)
            tm[t] = fmaxf(fmaxf(fmaxf(st[t][0], st[t][1]), st[t][2]), st[t][3]);
        const float a0 = fmaxf(fmaxf(tm[0], tm[1]), tm[2]);
        const float a1 = fmaxf(fmaxf(tm[3], tm[4]), tm[5]);
        const float a2 = fmaxf(fmaxf(tm[6], tm[7]), tm[8]);
        const float a3 = fmaxf(fmaxf(tm[9], tm[10]), tm[11]);
        const float a4 = fmaxf(fmaxf(tm[12], tm[13]), tm[14]);
        float rm = fmaxf(fmaxf(fmaxf(a0, a1), a2), fmaxf(fmaxf(a3, a4), tm[15]));
        rm = fmaxf(rm, __shfl_xor(rm, 16, 64));
        rm = fmaxf(rm, __shfl_xor(rm, 32, 64));

        // P = exp2(S - rm)  (scores pre-scaled by log2e/8 at Q-proj)
#pragma unroll
        for (int t = 0; t < 16; ++t)
#pragma unroll
            for (int rr = 0; rr < 4; ++rr)
                st[t][rr] = exp2f(st[t][rr] - rm);

        // opaque 0 offset: keep the 32 V ds_reads inside this iteration
        int vo = 0;
        asm volatile("" : "+v"(vo));

        // O^T = V_pi @ P^T : 4 hd-tiles + ones-tile (row sum), k = 256
        f32x4 o[4];
#pragma unroll
        for (int nt = 0; nt < 4; ++nt)
#pragma unroll
            for (int rr = 0; rr < 4; ++rr) o[nt][rr] = 0.f;
        f32x4 osum;
#pragma unroll
        for (int rr = 0; rr < 4; ++rr) osum[rr] = 0.f;

#pragma unroll
        for (int c = 0; c < 8; ++c) {
            // P^T B-frag: slot (quad, j) <-> kv = 32c + 16*(j>>2) + 4*quad + (j&3)
            union { fp16x2 h2[4]; f16x8 v; } pbu;
            pbu.h2[0] = __builtin_amdgcn_cvt_pkrtz(st[2 * c][0], st[2 * c][1]);
            pbu.h2[1] = __builtin_amdgcn_cvt_pkrtz(st[2 * c][2], st[2 * c][3]);
            pbu.h2[2] = __builtin_amdgcn_cvt_pkrtz(st[2 * c + 1][0], st[2 * c + 1][1]);
            pbu.h2[3] = __builtin_amdgcn_cvt_pkrtz(st[2 * c + 1][2], st[2 * c + 1][3]);
            const f16x8 pb = pbu.v;
            osum = MFMA16(ones, pb, osum);
#pragma unroll
            for (int nt = 0; nt < 4; ++nt) {
                const f16x8 va = *(const f16x8*)&Vs[(nt * 16 + l15) * 256 +
                                                   (((c * 4 + quad) ^ vsw) * 8) + vo];
                o[nt] = MFMA16(va, pb, o[nt]);
            }
        }

        // all rows of the ones-tile C equal the full row sum for q = l15
        const float ir = 1.0f / osum[0];

        // store: O^T C-frag: q = l15, hd = nt*16 + quad*4 + rr -> f16x4 packs
        const size_t rowbase = ((size_t)b * 4096 + q0 + qrow + l15) * 1024 + h * 64;
#pragma unroll
        for (int nt = 0; nt < 4; ++nt) {
            f16x4 ov;
#pragma unroll
            for (int rr = 0; rr < 4; ++rr) ov[rr] = (_Float16)(o[nt][rr] * ir);
            *(f16x4*)&attn[rowbase + nt * 16 + quad * 4] = ov;
        }

        bq0 = nq0; bq1 = nq1;
    }
}

// ---------------------------------------------------------------------------
extern "C" void kernel_launch(void* const* d_in, const int* in_sizes, int n_in,
                              void* d_out, int out_size, void* d_ws, size_t ws_size,
                              hipStream_t stream) {
    const float* patches = (const float*)d_in[0];
    const float* latents = (const float*)d_in[1];
    const float* Wq = (const float*)d_in[2];
    const float* bq = (const float*)d_in[3];
    const float* Wk = (const float*)d_in[4];
    const float* bk = (const float*)d_in[5];
    const float* Wv = (const float*)d_in[6];
    const float* bv = (const float*)d_in[7];
    const float* Wo = (const float*)d_in[8];
    const float* bo = (const float*)d_in[9];
    const int*   nf = (const int*)d_in[10];
    float* out = (float*)d_out;
    (void)in_sizes; (void)n_in; (void)out_size; (void)ws_size;

    char* p = (char*)d_ws;
    _Float16* WqT  = (_Float16*)p; p += (size_t)1024 * 1024 * 2;
    _Float16* WkvT = (_Float16*)p; p += (size_t)512 * 1024 * 2;
    _Float16* WoT  = (_Float16*)p; p += (size_t)1024 * 1024 * 2;
    float*    bkv  = (float*)p;    p += 4096;
    _Float16* p16  = (_Float16*)p; p += (size_t)4 * 4096 * 1024 * 2;
    _Float16* l16  = (_Float16*)p; p += (size_t)4 * 256 * 1024 * 2;
    _Float16* q_h  = (_Float16*)p; p += (size_t)4 * 16 * 4096 * 64 * 2;
    _Float16* k_h  = (_Float16*)p; p += (size_t)4 * 4 * 256 * 64 * 2;
    _Float16* v_pi = (_Float16*)p; p += (size_t)4 * 4 * 256 * 64 * 2;  // after k_h
    _Float16* attn_h = (_Float16*)p; p += (size_t)16384 * 1024 * 2;

    prep<<<18433, 256, 0, stream>>>((const float4*)patches, (const float4*)latents,
                                    (f16x4*)p16, (f16x4*)l16,
                                    Wq, Wk, Wv, Wo, WqT, WkvT, WoT, bk, bv, bkv);

    gemm32<1><<<dim3(4, 4), 256, 0, stream>>>(l16, WkvT, bkv, k_h, nf);
    gemm8p<0><<<256, 512, 0, stream>>>(p16, WqT, bq, q_h, nf);

    attn5<<<dim3(64, 8), 512, 0, stream>>>(q_h, k_h, v_pi, attn_h);

    gemm8p<2><<<256, 512, 0, stream>>>(attn_h, WoT, bo, out, nf);
}

// Round 8
// 263.179 us; speedup vs baseline: 1.1747x; 1.0699x over previous
//
#include <hip/hip_runtime.h>
#include <hip/hip_fp16.h>
#include <cstdint>

typedef _Float16 f16x8 __attribute__((ext_vector_type(8)));
typedef _Float16 f16x4 __attribute__((ext_vector_type(4)));
typedef __fp16   fp16x2 __attribute__((ext_vector_type(2)));  // cvt_pkrtz return type
typedef float    f32x4 __attribute__((ext_vector_type(4)));
typedef float    f32x16 __attribute__((ext_vector_type(16)));

#define MFMA16(a, b, c) __builtin_amdgcn_mfma_f32_16x16x32_f16((a), (b), (c), 0, 0, 0)
#define MFMA32(a, b, c) __builtin_amdgcn_mfma_f32_32x32x16_f16((a), (b), (c), 0, 0, 0)

// B=4, LQ=4096, LKV=256, D=1024, H=16, KVH=4, HD=64

__device__ __forceinline__ void async_cp16(const _Float16* g, _Float16* l) {
    __builtin_amdgcn_global_load_lds(
        (const __attribute__((address_space(1))) void*)g,
        (__attribute__((address_space(3))) void*)l, 16, 0, 0);
}

// ---------------------------------------------------------------------------
// prep: ONE launch fusing (a) fp32->fp16 convert of patches+latents,
// (b) all 4 weight transposes, (c) bkv concat.  No mutual deps; flat grid.
// ---------------------------------------------------------------------------
__global__ __launch_bounds__(256) void prep(
    const float4* __restrict__ patches, const float4* __restrict__ latents,
    f16x4* __restrict__ p16, f16x4* __restrict__ l16,
    const float* __restrict__ Wq, const float* __restrict__ Wk,
    const float* __restrict__ Wv, const float* __restrict__ Wo,
    _Float16* __restrict__ WqT, _Float16* __restrict__ WkvT,
    _Float16* __restrict__ WoT,
    const float* __restrict__ bk, const float* __restrict__ bv,
    float* __restrict__ bkv) {
    __shared__ float T[64][65];
    const int tid = threadIdx.x;
    const int bid = blockIdx.x;

    if (bid < 17408) {  // cvt
        const long i = (long)bid * 256 + tid;
        const float4 v = (i < 4194304) ? patches[i] : latents[i - 4194304];
        f16x4 o;
        o[0] = (_Float16)v.x; o[1] = (_Float16)v.y;
        o[2] = (_Float16)v.z; o[3] = (_Float16)v.w;
        if (i < 4194304) p16[i] = o; else l16[i - 4194304] = o;
        return;
    }
    if (bid == 18432) {  // catbias
        bkv[tid] = bk[tid];
        bkv[256 + tid] = bv[tid];
        return;
    }
    // transpose: fp32 [K][N] -> fp16 [N][K]
    const int t = bid - 17408;
    const int z = t >> 8, rem = t & 255, xb = rem & 15, yb = rem >> 4;
    const float* W;
    _Float16* WT;
    int Nd;
    if (z == 0)      { W = Wq; WT = WqT;                       Nd = 1024; }
    else if (z == 1) { W = Wk; WT = WkvT;                      Nd = 256;  }
    else if (z == 2) { W = Wv; WT = WkvT + (size_t)256 * 1024; Nd = 256;  }
    else             { W = Wo; WT = WoT;                       Nd = 1024; }
    const int n0 = xb * 64, k0 = yb * 64;
    if (n0 >= Nd) return;

    const int nl = tid & 63, kg = tid >> 6;
#pragma unroll
    for (int i = 0; i < 16; ++i) {
        const int kl = kg * 16 + i;
        T[kl][nl] = W[(size_t)(k0 + kl) * Nd + n0 + nl];
    }
    __syncthreads();
    const int kl = tid & 63;
#pragma unroll
    for (int i = 0; i < 16; ++i) {
        const int nl2 = kg * 16 + i;
        WT[(size_t)(n0 + nl2) * 1024 + k0 + kl] = (_Float16)T[kl][nl2];
    }
}

// ---------------------------------------------------------------------------
// KV-proj GEMM: 2-barrier structure, 128x128 tile (was 256x128: 16 blocks on
// 16 CUs left 240 idle; 32 blocks of half the work ~halves the makespan).
// 4 waves, wave tile 64m x 64n (2mt x 2nt of 32x32 MFMA).
// ---------------------------------------------------------------------------
template <int EPI>
__global__ __launch_bounds__(256, 2) void gemm32(const _Float16* __restrict__ A,
                                                 const _Float16* __restrict__ BT,
                                                 const float* __restrict__ bias,
                                                 void* __restrict__ Cp,
                                                 const int* __restrict__ nfp) {
    constexpr int K = 1024;
    __shared__ _Float16 As[128 * 64];
    __shared__ _Float16 Bs[128 * 64];

    const int tid = threadIdx.x;
    const int lane = tid & 63, l31 = lane & 31, hh = lane >> 5;
    const int w = tid >> 6, wm = w >> 1, wn = w & 1;

    const int n0 = blockIdx.x * 128;
    const int m0 = blockIdx.y * 128;

    f32x16 acc[2][2];
#pragma unroll
    for (int mt = 0; mt < 2; ++mt)
#pragma unroll
        for (int nt = 0; nt < 2; ++nt)
#pragma unroll
            for (int v = 0; v < 16; ++v) acc[mt][nt][v] = 0.f;

    for (int k0 = 0; k0 < K; k0 += 64) {
#pragma unroll
        for (int i = 0; i < 4; ++i) {
            const int id = i * 256 + tid;
            const int r = id >> 3;
            const int c = (id & 7) ^ (r & 7);
            async_cp16(A + (size_t)(m0 + r) * K + k0 + c * 8,
                       As + i * 2048 + w * 512);
        }
#pragma unroll
        for (int i = 0; i < 4; ++i) {
            const int id = i * 256 + tid;
            const int r = id >> 3;
            const int c = (id & 7) ^ (r & 7);
            async_cp16(BT + (size_t)(n0 + r) * K + k0 + c * 8,
                       Bs + i * 2048 + w * 512);
        }
        __syncthreads();

#pragma unroll
        for (int kk = 0; kk < 4; ++kk) {
            f16x8 af[2], bf[2];
#pragma unroll
            for (int mt = 0; mt < 2; ++mt) {
                const int row = wm * 64 + mt * 32 + l31;
                const int pc = (kk * 2 + hh) ^ (row & 7);
                af[mt] = *(const f16x8*)&As[row * 64 + pc * 8];
            }
#pragma unroll
            for (int nt = 0; nt < 2; ++nt) {
                const int row = wn * 64 + nt * 32 + l31;
                const int pc = (kk * 2 + hh) ^ (row & 7);
                bf[nt] = *(const f16x8*)&Bs[row * 64 + pc * 8];
            }
#pragma unroll
            for (int mt = 0; mt < 2; ++mt)
#pragma unroll
                for (int nt = 0; nt < 2; ++nt)
                    acc[mt][nt] = MFMA32(af[mt], bf[nt], acc[mt][nt]);
        }
        __syncthreads();
    }

    const int nf = nfp[0];
    const int nbase = n0 + wn * 64;

    float bb[2];
#pragma unroll
    for (int nt = 0; nt < 2; ++nt) bb[nt] = bias[nbase + nt * 32 + l31];
#pragma unroll
    for (int mt = 0; mt < 2; ++mt)
#pragma unroll
        for (int nt = 0; nt < 2; ++nt)
#pragma unroll
            for (int v = 0; v < 16; ++v) acc[mt][nt][v] += bb[nt];

    {  // K/V fused (N=512)
        _Float16* kout = (_Float16*)Cp;
        _Float16* vout = kout + (size_t)4 * 4 * 256 * 64;
        if (nbase < 256) {
            const float l2b = 13.287712379549449f;
            const float inv = exp2f(-((float)l31 * (1.0f / 32.0f)) * l2b);
            const int dv = 256 / (nf > 1 ? nf : 1);
            const int kvh = nbase >> 6;
#pragma unroll
            for (int mt = 0; mt < 2; ++mt) {
#pragma unroll
                for (int v = 0; v < 16; ++v) {
                    const int m = m0 + wm * 64 + mt * 32 + (v & 3) + 8 * (v >> 2) + 4 * hh;
                    const int b = m >> 8, lkv = m & 255;
                    if (nf > 1) {
                        const int pos = lkv / dv;
                        float s, c;
                        __sincosf((float)pos * inv, &s, &c);
                        const float x1 = acc[mt][0][v], x2 = acc[mt][1][v];
                        acc[mt][0][v] = x1 * c - x2 * s;
                        acc[mt][1][v] = x2 * c + x1 * s;
                    }
#pragma unroll
                    for (int nt = 0; nt < 2; ++nt) {
                        const int hd = nt * 32 + l31;
                        kout[(((size_t)(b * 4 + kvh)) * 256 + lkv) * 64 + hd] =
                            (_Float16)acc[mt][nt][v];
                    }
                }
            }
        } else {
            const int kvh = (nbase - 256) >> 6;
#pragma unroll
            for (int mt = 0; mt < 2; ++mt) {
#pragma unroll
                for (int v = 0; v < 16; ++v) {
                    const int m = m0 + wm * 64 + mt * 32 + (v & 3) + 8 * (v >> 2) + 4 * hh;
                    const int b = m >> 8, lkv = m & 255;
                    // pi-permuted kv slot: swap the 16s bit below the 4s bits
                    const int s = (lkv & 0xE0) | ((lkv & 12) << 1) |
                                  ((lkv & 16) >> 2) | (lkv & 3);
#pragma unroll
                    for (int nt = 0; nt < 2; ++nt) {
                        const int hd = nt * 32 + l31;
                        vout[(((size_t)(b * 4 + kvh)) * 64 + hd) * 256 + s] =
                            (_Float16)acc[mt][nt][v];
                    }
                }
            }
        }
    }
}

// ---------------------------------------------------------------------------
// 8-phase 256x256 GEMM (T2+T3+T4+T5).  EPI 0: Q-proj (bias+RoPE, scale folds
// log2e/8 so attn can use exp2 directly).  EPI 2: O-proj (fp32).
// ---------------------------------------------------------------------------
template <int EPI>
__global__ __launch_bounds__(512, 2) void gemm8p(const _Float16* __restrict__ A,
                                                 const _Float16* __restrict__ BT,
                                                 const float* __restrict__ bias,
                                                 void* __restrict__ Cp,
                                                 const int* __restrict__ nfp) {
    constexpr int K = 1024;
    __shared__ alignas(16) _Float16 lds[2][2][2][128 * 64];  // [buf][A=0/B=1][half]

    const int tid = threadIdx.x;
    const int lane = tid & 63, quad = lane >> 4, l15 = lane & 15;
    const int w = tid >> 6, wm = w >> 2, wn = w & 3;

    // bijective XCD swizzle: 256 blocks, 8 XCDs -> 32-block m-stripes
    int lin = blockIdx.x;
    lin = (lin & 7) * 32 + (lin >> 3);
    const int m0 = (lin >> 2) * 256;
    const int n0 = (lin & 3) * 256;

    f32x4 acc[8][4];
#pragma unroll
    for (int mf = 0; mf < 8; ++mf)
#pragma unroll
        for (int nf = 0; nf < 4; ++nf)
#pragma unroll
            for (int rr = 0; rr < 4; ++rr) acc[mf][nf][rr] = 0.f;

    f16x8 ra[4][2], rb[4][2];

#define STAGE(BUF, MAT, HALF, KK0)                                              \
    {                                                                           \
        const _Float16* g_ = (MAT) ? BT : A;                                    \
        const int rb_ = ((MAT) ? n0 : m0) + (HALF) * 128;                       \
        _Float16* dst_ = &lds[BUF][MAT][HALF][0];                               \
        _Pragma("unroll") for (int i_ = 0; i_ < 2; ++i_) {                      \
            const int id_ = i_ * 512 + tid;                                     \
            const int r_ = id_ >> 3;                                            \
            const int c_ = (id_ & 7) ^ (r_ & 7);                                \
            async_cp16(g_ + (size_t)(rb_ + r_) * K + (KK0) + c_ * 8,            \
                       dst_ + i_ * 4096 + w * 512);                             \
        }                                                                       \
    }

#define LDA4(BUF, MH)                                                           \
    _Pragma("unroll") for (int i_ = 0; i_ < 4; ++i_)                            \
    _Pragma("unroll") for (int ks_ = 0; ks_ < 2; ++ks_) {                       \
        const int row_ = ((MH) * 4 + i_) * 16 + l15;                            \
        ra[i_][ks_] = *(const f16x8*)&lds[BUF][0][wm]                           \
            [row_ * 64 + (((ks_ * 4 + quad) ^ (l15 & 7)) * 8)];                 \
    }

#define LDB2(BUF, NFROM)                                                        \
    _Pragma("unroll") for (int j_ = 0; j_ < 2; ++j_)                            \
    _Pragma("unroll") for (int ks_ = 0; ks_ < 2; ++ks_) {                       \
        const int nf_ = (NFROM) + j_;                                           \
        const int row_ = (wn & 1) * 64 + nf_ * 16 + l15;                        \
        rb[nf_][ks_] = *(const f16x8*)&lds[BUF][1][wn >> 1]                     \
            [row_ * 64 + (((ks_ * 4 + quad) ^ (l15 & 7)) * 8)];                 \
    }

#define QUAD(QM, QN)                                                            \
    {                                                                           \
        __builtin_amdgcn_s_setprio(1);                                          \
        _Pragma("unroll") for (int i_ = 0; i_ < 4; ++i_)                        \
        _Pragma("unroll") for (int j_ = 0; j_ < 2; ++j_)                        \
        _Pragma("unroll") for (int ks_ = 0; ks_ < 2; ++ks_)                     \
            acc[(QM) * 4 + i_][(QN) * 2 + j_] =                                 \
                MFMA16(ra[i_][ks_], rb[(QN) * 2 + j_][ks_],                     \
                       acc[(QM) * 4 + i_][(QN) * 2 + j_]);                      \
        __builtin_amdgcn_s_setprio(0);                                          \
    }

#define FENCE() asm volatile("" ::: "memory")
#define BARR()  FENCE(); __builtin_amdgcn_s_barrier(); FENCE()
#define LGKM0() asm volatile("s_waitcnt lgkmcnt(0)" ::: "memory");              \
                __builtin_amdgcn_sched_barrier(0)
#define VMC4()  asm volatile("s_waitcnt vmcnt(4)" ::: "memory")

    // prologue: tile0 (all 4 halves) + tile1 (B0, A0)
    STAGE(0, 1, 0, 0);
    STAGE(0, 1, 1, 0);
    STAGE(0, 0, 0, 0);
    STAGE(0, 0, 1, 0);
    STAGE(1, 1, 0, 64);
    STAGE(1, 0, 0, 64);
    VMC4();
    BARR();

    int k0 = 0;
#pragma unroll 1
    for (int it = 0; it < 8; ++it) {
        const int k_t1 = k0 + 64;
        const int k_n0 = (k0 + 128 < K) ? k0 + 128 : K - 64;  // tile t0+2
        const int k_n1 = (k0 + 192 < K) ? k0 + 192 : K - 64;  // tile t1+2
        // P0
        LDA4(0, 0); LDB2(0, 0);
        STAGE(1, 1, 1, k_t1);
        BARR(); LGKM0(); QUAD(0, 0); BARR();
        // P1
        LDB2(0, 2);
        STAGE(1, 0, 1, k_t1);
        BARR(); LGKM0(); QUAD(0, 1); BARR();
        // P2
        LDA4(0, 1);
        STAGE(0, 1, 0, k_n0);
        BARR(); LGKM0(); QUAD(1, 0); BARR();
        // P3
        STAGE(0, 1, 1, k_n0);
        BARR(); LGKM0(); QUAD(1, 1); VMC4(); BARR();
        // P4
        LDA4(1, 0); LDB2(1, 0);
        STAGE(0, 0, 0, k_n0);
        BARR(); LGKM0(); QUAD(0, 0); BARR();
        // P5
        LDB2(1, 2);
        STAGE(0, 0, 1, k_n0);
        BARR(); LGKM0(); QUAD(0, 1); BARR();
        // P6
        LDA4(1, 1);
        STAGE(1, 1, 0, k_n1);
        BARR(); LGKM0(); QUAD(1, 0); BARR();
        // P7
        STAGE(1, 0, 0, k_n1);
        BARR(); LGKM0(); QUAD(1, 1); VMC4(); BARR();
        k0 += 128;
    }
    asm volatile("s_waitcnt vmcnt(0)" ::: "memory");

    // ---- epilogue: m = m0 + wm*128 + mf*16 + quad*4 + rr,
    //                n = n0 + wn*64 + nf*16 + l15
    const int nf_frames = nfp[0];
    float bb[4];
#pragma unroll
    for (int nf = 0; nf < 4; ++nf) bb[nf] = bias[n0 + wn * 64 + nf * 16 + l15];
#pragma unroll
    for (int mf = 0; mf < 8; ++mf)
#pragma unroll
        for (int nf = 0; nf < 4; ++nf)
#pragma unroll
            for (int rr = 0; rr < 4; ++rr) acc[mf][nf][rr] += bb[nf];

    if constexpr (EPI == 0) {  // Q-proj: RoPE + scale -> q_h[b][h][lq][hd]
        // scale = 0.125 * log2(e): softmax then uses exp2 directly
        const float SCALE = 0.18033688011112042f;
        const float l2b = 13.287712379549449f;
        const float inv0 = exp2f(-((float)l15 * (1.0f / 32.0f)) * l2b);
        const float inv1 = exp2f(-((float)(16 + l15) * (1.0f / 32.0f)) * l2b);
        _Float16* O = (_Float16*)Cp;
        const int head = (n0 + wn * 64) >> 6;
        int dv = 4096;
        bool uni = false;
        float us0 = 0.f, uc0 = 1.f, us1 = 0.f, uc1 = 1.f;
        if (nf_frames > 1) {
            dv = 4096 / nf_frames;
            const int lqb = (m0 + wm * 128) & 4095;
            uni = (lqb / dv) == ((lqb + 127) / dv);
            if (uni) {
                const float fp = (float)(lqb / dv);
                __sincosf(fp * inv0, &us0, &uc0);
                __sincosf(fp * inv1, &us1, &uc1);
            }
        }
#pragma unroll
        for (int mf = 0; mf < 8; ++mf) {
#pragma unroll
            for (int rr = 0; rr < 4; ++rr) {
                const int m = m0 + wm * 128 + mf * 16 + quad * 4 + rr;
                const int b = m >> 12, lq = m & 4095;
                if (nf_frames > 1) {
                    float s0, c0, s1, c1;
                    if (uni) {
                        s0 = us0; c0 = uc0; s1 = us1; c1 = uc1;
                    } else {
                        const int pos = lq / dv;
                        __sincosf((float)pos * inv0, &s0, &c0);
                        __sincosf((float)pos * inv1, &s1, &c1);
                    }
                    const float x0 = acc[mf][0][rr], x2 = acc[mf][2][rr];
                    const float x1 = acc[mf][1][rr], x3 = acc[mf][3][rr];
                    acc[mf][0][rr] = x0 * c0 - x2 * s0;
                    acc[mf][2][rr] = x2 * c0 + x0 * s0;
                    acc[mf][1][rr] = x1 * c1 - x3 * s1;
                    acc[mf][3][rr] = x3 * c1 + x1 * s1;
                }
                const size_t base = (((size_t)(b * 16 + head)) * 4096 + lq) * 64;
#pragma unroll
                for (int nf = 0; nf < 4; ++nf)
                    O[base + nf * 16 + l15] = (_Float16)(acc[mf][nf][rr] * SCALE);
            }
        }
    } else {  // O-proj fp32 row-major
        float* O = (float*)Cp;
#pragma unroll
        for (int mf = 0; mf < 8; ++mf) {
#pragma unroll
            for (int rr = 0; rr < 4; ++rr) {
                const int m = m0 + wm * 128 + mf * 16 + quad * 4 + rr;
#pragma unroll
                for (int nf = 0; nf < 4; ++nf)
                    O[(size_t)m * 1024 + n0 + wn * 64 + nf * 16 + l15] =
                        acc[mf][nf][rr];
            }
        }
    }
#undef STAGE
#undef LDA4
#undef LDB2
#undef QUAD
#undef FENCE
#undef BARR
#undef LGKM0
#undef VMC4
}

// ---------------------------------------------------------------------------
// Attention v9: 8 waves, K+V LDS swizzled, Q prefetch, chunk rotation,
// exp2-folded scale, ones-MFMA row-sum, pkrtz pack, launch_bounds(512,2)
// (st[16] in arch VGPRs -- no AGPR move traffic).
// ---------------------------------------------------------------------------
__global__ __launch_bounds__(512, 2) void attn5(const _Float16* __restrict__ qh,
                                                const _Float16* __restrict__ kh,
                                                const _Float16* __restrict__ vp,
                                                _Float16* __restrict__ attn) {
    __shared__ _Float16 Ks[256 * 64];  // swizzled: chunk c of row r at c^(r&7)
    __shared__ _Float16 Vs[64 * 256];  // swizzled: chunk s of row hd at s^((hd&7)<<2)

    const int tid = threadIdx.x;
    const int w = tid >> 6, lane = tid & 63, quad = lane >> 4, l15 = lane & 15;
    const int bh = blockIdx.x, b = bh >> 4, h = bh & 15, kvh = h >> 2;
    const int q0 = blockIdx.y * 512;

    const _Float16* kb = kh + (size_t)(b * 4 + kvh) * 256 * 64;
    const _Float16* vb = vp + (size_t)(b * 4 + kvh) * 64 * 256;
    const _Float16* qb = qh + ((size_t)bh * 4096 + q0) * 64;

    // ---- stage K into LDS (2048 x 16B chunks, 4/thread), source-swizzled
#pragma unroll
    for (int i = 0; i < 4; ++i) {
        const int id = i * 512 + tid;
        const int r = id >> 3;
        const int c = (id & 7) ^ (r & 7);
        async_cp16(kb + (size_t)r * 64 + c * 8, Ks + i * 4096 + w * 512);
    }
    // ---- stage V_pi into LDS (2048 x 16B chunks), source-swizzled
#pragma unroll
    for (int i = 0; i < 4; ++i) {
        const int id = i * 512 + tid;
        const int hd = id >> 5;
        const int s5 = id & 31;
        const int c = s5 ^ ((hd & 7) << 2);
        async_cp16(vb + (size_t)hd * 256 + c * 8, Vs + i * 4096 + w * 512);
    }
    __syncthreads();

    const int sw = l15 & 7;        // K read-side swizzle key (row&7 == l15&7)
    const int p0 = quad ^ sw;      // slot of k-chunk quad (hd 0..31)
    const int vsw = sw << 2;       // V read-side swizzle key (hd&7 == l15&7)
    const int crot = w & 3;        // per-wave chunk rotation (de-convoy)

    f16x8 ones;
#pragma unroll
    for (int j = 0; j < 8; ++j) ones[j] = (_Float16)1.0f;

    // prefetch Q for first chunk
    const _Float16* qpre = qb + (size_t)(w * 64 + crot * 16 + l15) * 64 + quad * 8;
    f16x8 bq0 = *(const f16x8*)qpre;
    f16x8 bq1 = *(const f16x8*)(qpre + 32);

#pragma unroll 1
    for (int cc = 0; cc < 4; ++cc) {
        const int chunk = (cc + crot) & 3;
        const int qrow = w * 64 + chunk * 16;

        // issue next chunk's Q loads now; consumed next iteration
        const int nchunk = (cc + 1 + crot) & 3;
        const _Float16* np = qb + (size_t)(w * 64 + nchunk * 16 + l15) * 64 + quad * 8;
        const f16x8 nq0 = *(const f16x8*)np;
        const f16x8 nq1 = *(const f16x8*)(np + 32);

        // S^T = K @ Q^T : lane holds S[q=l15][kv = t*16 + quad*4 + rr]
        f32x4 st[16];
#pragma unroll
        for (int t = 0; t < 16; ++t)
#pragma unroll
            for (int rr = 0; rr < 4; ++rr) st[t][rr] = 0.f;

#pragma unroll
        for (int t = 0; t < 16; ++t) {
            const int row = t * 16 + l15;
            const f16x8 ka0 = *(const f16x8*)&Ks[row * 64 + p0 * 8];
            const f16x8 ka1 = *(const f16x8*)&Ks[row * 64 + (p0 ^ 4) * 8];
            st[t] = MFMA16(ka0, bq0, st[t]);
            st[t] = MFMA16(ka1, bq1, st[t]);
        }

        // row max (q = l15): fmax tree, then 2 shuffles
        float tm[16];
#pragma unroll
        for (int t = 0; t < 16; ++t)
            tm[t] = fmaxf(fmaxf(fmaxf(st[t][0], st[t][1]), st[t][2]), st[t][3]);
        const float a0 = fmaxf(fmaxf(tm[0], tm[1]), tm[2]);
        const float a1 = fmaxf(fmaxf(tm[3], tm[4]), tm[5]);
        const float a2 = fmaxf(fmaxf(tm[6], tm[7]), tm[8]);
        const float a3 = fmaxf(fmaxf(tm[9], tm[10]), tm[11]);
        const float a4 = fmaxf(fmaxf(tm[12], tm[13]), tm[14]);
        float rm = fmaxf(fmaxf(fmaxf(a0, a1), a2), fmaxf(fmaxf(a3, a4), tm[15]));
        rm = fmaxf(rm, __shfl_xor(rm, 16, 64));
        rm = fmaxf(rm, __shfl_xor(rm, 32, 64));

        // P = exp2(S - rm)  (scores pre-scaled by log2e/8 at Q-proj)
#pragma unroll
        for (int t = 0; t < 16; ++t)
#pragma unroll
            for (int rr = 0; rr < 4; ++rr)
                st[t][rr] = exp2f(st[t][rr] - rm);

        // opaque 0 offset: keep the 32 V ds_reads inside this iteration
        int vo = 0;
        asm volatile("" : "+v"(vo));

        // O^T = V_pi @ P^T : 4 hd-tiles + ones-tile (row sum), k = 256
        f32x4 o[4];
#pragma unroll
        for (int nt = 0; nt < 4; ++nt)
#pragma unroll
            for (int rr = 0; rr < 4; ++rr) o[nt][rr] = 0.f;
        f32x4 osum;
#pragma unroll
        for (int rr = 0; rr < 4; ++rr) osum[rr] = 0.f;

#pragma unroll
        for (int c = 0; c < 8; ++c) {
            // P^T B-frag: slot (quad, j) <-> kv = 32c + 16*(j>>2) + 4*quad + (j&3)
            union { fp16x2 h2[4]; f16x8 v; } pbu;
            pbu.h2[0] = __builtin_amdgcn_cvt_pkrtz(st[2 * c][0], st[2 * c][1]);
            pbu.h2[1] = __builtin_amdgcn_cvt_pkrtz(st[2 * c][2], st[2 * c][3]);
            pbu.h2[2] = __builtin_amdgcn_cvt_pkrtz(st[2 * c + 1][0], st[2 * c + 1][1]);
            pbu.h2[3] = __builtin_amdgcn_cvt_pkrtz(st[2 * c + 1][2], st[2 * c + 1][3]);
            const f16x8 pb = pbu.v;
            osum = MFMA16(ones, pb, osum);
#pragma unroll
            for (int nt = 0; nt < 4; ++nt) {
                const f16x8 va = *(const f16x8*)&Vs[(nt * 16 + l15) * 256 +
                                                   (((c * 4 + quad) ^ vsw) * 8) + vo];
                o[nt] = MFMA16(va, pb, o[nt]);
            }
        }

        // all rows of the ones-tile C equal the full row sum for q = l15
        const float ir = 1.0f / osum[0];

        // store: O^T C-frag: q = l15, hd = nt*16 + quad*4 + rr -> f16x4 packs
        const size_t rowbase = ((size_t)b * 4096 + q0 + qrow + l15) * 1024 + h * 64;
#pragma unroll
        for (int nt = 0; nt < 4; ++nt) {
            f16x4 ov;
#pragma unroll
            for (int rr = 0; rr < 4; ++rr) ov[rr] = (_Float16)(o[nt][rr] * ir);
            *(f16x4*)&attn[rowbase + nt * 16 + quad * 4] = ov;
        }

        bq0 = nq0; bq1 = nq1;
    }
}

// ---------------------------------------------------------------------------
extern "C" void kernel_launch(void* const* d_in, const int* in_sizes, int n_in,
                              void* d_out, int out_size, void* d_ws, size_t ws_size,
                              hipStream_t stream) {
    const float* patches = (const float*)d_in[0];
    const float* latents = (const float*)d_in[1];
    const float* Wq = (const float*)d_in[2];
    const float* bq = (const float*)d_in[3];
    const float* Wk = (const float*)d_in[4];
    const float* bk = (const float*)d_in[5];
    const float* Wv = (const float*)d_in[6];
    const float* bv = (const float*)d_in[7];
    const float* Wo = (const float*)d_in[8];
    const float* bo = (const float*)d_in[9];
    const int*   nf = (const int*)d_in[10];
    float* out = (float*)d_out;
    (void)in_sizes; (void)n_in; (void)out_size; (void)ws_size;

    char* p = (char*)d_ws;
    _Float16* WqT  = (_Float16*)p; p += (size_t)1024 * 1024 * 2;
    _Float16* WkvT = (_Float16*)p; p += (size_t)512 * 1024 * 2;
    _Float16* WoT  = (_Float16*)p; p += (size_t)1024 * 1024 * 2;
    float*    bkv  = (float*)p;    p += 4096;
    _Float16* p16  = (_Float16*)p; p += (size_t)4 * 4096 * 1024 * 2;
    _Float16* l16  = (_Float16*)p; p += (size_t)4 * 256 * 1024 * 2;
    _Float16* q_h  = (_Float16*)p; p += (size_t)4 * 16 * 4096 * 64 * 2;
    _Float16* k_h  = (_Float16*)p; p += (size_t)4 * 4 * 256 * 64 * 2;
    _Float16* v_pi = (_Float16*)p; p += (size_t)4 * 4 * 256 * 64 * 2;  // after k_h
    // attn_h aliases p16: p16 dies at gemm8p<0>; attn_h born at attn5.
    _Float16* attn_h = p16;

    prep<<<18433, 256, 0, stream>>>((const float4*)patches, (const float4*)latents,
                                    (f16x4*)p16, (f16x4*)l16,
                                    Wq, Wk, Wv, Wo, WqT, WkvT, WoT, bk, bv, bkv);

    gemm32<1><<<dim3(4, 8), 256, 0, stream>>>(l16, WkvT, bkv, k_h, nf);
    gemm8p<0><<<256, 512, 0, stream>>>(p16, WqT, bq, q_h, nf);

    attn5<<<dim3(64, 8), 512, 0, stream>>>(q_h, k_h, v_pi, attn_h);

    gemm8p<2><<<256, 512, 0, stream>>>(attn_h, WoT, bo, out, nf);
}